// Round 10
// baseline (1472.442 us; speedup 1.0000x reference)
//
#include <hip/hip_runtime.h>
#include <math.h>

#define D      256
#define K      16384
#define NPTS   8192
#define DELTA  0.2f
#define LCAP   2048
#define MAXCAP 4000000u

// d_out layout (all f32): zq[8,256,32,32] | indices[8192] | bit[8,32,32,256] | loss[1]
#define O_IDX  2097152
#define O_BIT  2105344
#define O_LOSS 4202496

typedef __attribute__((ext_vector_type(8))) short bf16x8;
typedef __attribute__((ext_vector_type(4))) float f32x4;
typedef unsigned long long u64;

__device__ __forceinline__ unsigned f2s(float f) {
    unsigned u = __float_as_uint(f);
    return (u & 0x80000000u) ? ~u : (u | 0x80000000u);
}
__device__ __forceinline__ float s2f(unsigned s) {
    return __uint_as_float((s & 0x80000000u) ? (s & 0x7fffffffu) : ~s);
}
__device__ __forceinline__ unsigned short f2bf(float f) {  // RNE
    unsigned u = __float_as_uint(f);
    u += 0x7fffu + ((u >> 16) & 1u);
    return (unsigned short)(u >> 16);
}

// async global->LDS, 16B per lane (wave-uniform base + lane*16 dest)
__device__ __forceinline__ void gload16(const unsigned short* g, unsigned short* l) {
    __builtin_amdgcn_global_load_lds(
        (const __attribute__((address_space(1))) unsigned int*)g,
        (__attribute__((address_space(3))) unsigned int*)l, 16, 0, 0);
}

// generic LDS pointer -> 32-bit LDS byte offset for inline-asm ds_read
__device__ __forceinline__ unsigned lds_off(const void* p) {
    return (unsigned)(size_t)(const __attribute__((address_space(3))) void*)p;
}

// k-major fragment layouts: X[(k>>3)][row][8] bf16, 16B per (row, k-chunk)
//   zfbT: [32][NPTS][8] bf16 ; ewbT: [32][K][8] bf16

// ---- merged prep: blocks [0,512) codebook; [512,640) z transpose; state init folded ----
__global__ __launch_bounds__(256) void prep(const float* __restrict__ E,
                                            const float* __restrict__ z,
                                            float* __restrict__ den,
                                            unsigned short* __restrict__ ewbT,
                                            unsigned short* __restrict__ zfbT,
                                            float* __restrict__ zf32,
                                            unsigned* __restrict__ gmax,
                                            u64* __restrict__ keys,
                                            unsigned* __restrict__ cnt) {
    const int blk = blockIdx.x, tid = threadIdx.x;
    if (blk < 512) {
        const int lane = tid & 63, wave = tid >> 6;
        if (blk < 32)        gmax[blk * 256 + tid] = 0u;
        else if (blk < 64)   keys[(blk - 32) * 256 + tid] = 0ull;
        else if (blk == 64 && tid < 2) cnt[tid] = 0u;
        #pragma unroll
        for (int j = 0; j < 8; ++j) {
            const int row = blk * 32 + wave * 8 + j;
            const float4 v = *(const float4*)(E + (size_t)row * D + lane * 4);
            float ss = v.x * v.x + v.y * v.y + v.z * v.z + v.w * v.w;
            #pragma unroll
            for (int o = 1; o < 64; o <<= 1) ss += __shfl_xor(ss, o);
            const float dn = fmaxf(sqrtf(ss), 1e-12f);
            const unsigned lo = (unsigned)f2bf(v.x / dn) | ((unsigned)f2bf(v.y / dn) << 16);
            const unsigned hi = (unsigned)f2bf(v.z / dn) | ((unsigned)f2bf(v.w / dn) << 16);
            // k = lane*4 .. +4 -> chunk lane>>1, offset (lane&1)*4
            *(uint2*)(ewbT + ((size_t)(lane >> 1) * K + row) * 8 + (lane & 1) * 4)
                = make_uint2(lo, hi);
            if (lane == 0) den[row] = dn;
        }
    } else {
        const int bi = blk - 512;
        const int b = bi >> 4, hw0 = (bi & 15) * 64;
        __shared__ float t[64][65];
        for (int dc = 0; dc < D; dc += 64) {
            #pragma unroll
            for (int it = 0; it < 16; ++it) {
                const int idx = it * 256 + tid;
                const int dl = idx >> 6, hw = idx & 63;
                t[dl][hw] = z[(size_t)(b * 256 + dc + dl) * 1024 + hw0 + hw];
            }
            __syncthreads();
            // zf32: original lane mapping (consecutive lanes -> consecutive k) = coalesced f32
            #pragma unroll
            for (int it = 0; it < 16; ++it) {
                const int idx = it * 256 + tid;
                const int pl = idx >> 6, dl = idx & 63;
                zf32[(size_t)(b * 1024 + hw0 + pl) * D + dc + dl] = t[dl][pl];
            }
            // zfbT: vectorized pass (consecutive lanes -> consecutive p) = coalesced 16B stores
            // (was: scalar 2B scattered stores)
            #pragma unroll
            for (int tk = 0; tk < 2; ++tk) {
                const int task = tk * 256 + tid;
                const int ch = task >> 6, pl = task & 63;
                const int p = b * 1024 + hw0 + pl;
                unsigned short u[8];
                #pragma unroll
                for (int j = 0; j < 8; ++j) u[j] = f2bf(t[ch * 8 + j][pl]);
                *(uint4*)(zfbT + ((size_t)((dc >> 3) + ch) * NPTS + p) * 8) = *(uint4*)u;
            }
            __syncthreads();
        }
    }
}

// ================= 256x256 8-phase GEMM core (round-7 structure, reverted) =================
#define SBAR  __builtin_amdgcn_sched_barrier(0);
#define BARR  __builtin_amdgcn_s_barrier();
#define VMC(N) asm volatile("s_waitcnt vmcnt(" N ")");
#define LGKM_SB  asm volatile("s_waitcnt lgkmcnt(0)"); __builtin_amdgcn_sched_barrier(0);

#define STG_A(slot, t, kk)                                                          \
    do {                                                                            \
        const int cA1_ = (kk) * 4 + hi_, cA2_ = (kk) * 4 + 2 + hi_;                 \
        gload16(zfbT + ((size_t)((t) * 8 + cA1_) * NPTS + m0 + (th_ ^ (cA1_ << 1))) * 8, \
                &sA[slot][cA1_][th_][0]);                                           \
        gload16(zfbT + ((size_t)((t) * 8 + cA2_) * NPTS + m0 + (th_ ^ (cA2_ << 1))) * 8, \
                &sA[slot][cA2_][th_][0]);                                           \
    } while (0)

#define STG_B(slot, t, kk)                                                          \
    do {                                                                            \
        const int cB1_ = (kk) * 4 + hi_, cB2_ = (kk) * 4 + 2 + hi_;                 \
        gload16(ewbT + ((size_t)((t) * 8 + cB1_) * K + n0 + (th_ ^ (cB1_ << 1))) * 8, \
                &sB[slot][cB1_][th_][0]);                                           \
        gload16(ewbT + ((size_t)((t) * 8 + cB2_) * K + n0 + (th_ ^ (cB2_ << 1))) * 8, \
                &sB[slot][cB2_][th_][0]);                                           \
    } while (0)

#define RD_A(slot, kO, mg)                                                          \
    do {                                                                            \
        const unsigned a__ = sAb_ + (unsigned)((slot) * 32768 + (mg) * 1024) + (kO);\
        asm volatile("ds_read_b128 %0, %1"            : "=v"(af_[0]) : "v"(a__));   \
        asm volatile("ds_read_b128 %0, %1 offset:256" : "=v"(af_[1]) : "v"(a__));   \
        asm volatile("ds_read_b128 %0, %1 offset:512" : "=v"(af_[2]) : "v"(a__));   \
        asm volatile("ds_read_b128 %0, %1 offset:768" : "=v"(af_[3]) : "v"(a__));   \
    } while (0)

#define RD_B(slot, kO)                                                              \
    do {                                                                            \
        const unsigned b__ = sBb_ + (unsigned)((slot) * 32768) + (kO);              \
        asm volatile("ds_read_b128 %0, %1"            : "=v"(bf_[0]) : "v"(b__));   \
        asm volatile("ds_read_b128 %0, %1 offset:256" : "=v"(bf_[1]) : "v"(b__));   \
        asm volatile("ds_read_b128 %0, %1 offset:512" : "=v"(bf_[2]) : "v"(b__));   \
        asm volatile("ds_read_b128 %0, %1 offset:768" : "=v"(bf_[3]) : "v"(b__));   \
    } while (0)

#define MF(mg)                                                                      \
    do {                                                                            \
        __builtin_amdgcn_s_setprio(1);                                              \
        _Pragma("unroll")                                                           \
        for (int j_ = 0; j_ < 4; ++j_)                                              \
            _Pragma("unroll")                                                       \
            for (int nt_ = 0; nt_ < 4; ++nt_)                                       \
                acc[(mg) * 4 + j_][nt_] = __builtin_amdgcn_mfma_f32_16x16x32_bf16(  \
                    af_[j_], bf_[nt_], acc[(mg) * 4 + j_][nt_], 0, 0, 0);           \
        __builtin_amdgcn_s_setprio(0);                                              \
    } while (0)

#define KTILE(slot, SA0, SB0, SA1, SB1, V1, V2)                                     \
    RD_A(slot, aOff0_, 0); RD_B(slot, bOff0_); SA0; SBAR BARR LGKM_SB MF(0); SBAR BARR SBAR \
    RD_A(slot, aOff0_, 1);                     SB0; SBAR BARR LGKM_SB MF(1); SBAR VMC(V1) BARR SBAR \
    RD_A(slot, aOff1_, 0); RD_B(slot, bOff1_); SA1; SBAR BARR LGKM_SB MF(0); SBAR BARR SBAR \
    RD_A(slot, aOff1_, 1);                     SB1; SBAR BARR LGKM_SB MF(1); SBAR V2 BARR SBAR

#define GEMM_PRELUDE()                                                              \
    __shared__ unsigned short sA[2][8][256][8];                                     \
    __shared__ unsigned short sB[2][8][256][8];                                     \
    f32x4 acc[8][4];                                                                \
    _Pragma("unroll")                                                               \
    for (int i_ = 0; i_ < 8; ++i_)                                                  \
        _Pragma("unroll")                                                           \
        for (int j_ = 0; j_ < 4; ++j_) acc[i_][j_] = (f32x4){0.f, 0.f, 0.f, 0.f};   \
    bf16x8 af_[4], bf_[4];                                                          \
    const int th_ = tid & 255, hi_ = tid >> 8;                                      \
    const int aRow_ = wm * 128 + col, bRow_ = wn * 64 + col;                        \
    const unsigned sAb_ = lds_off(&sA[0][0][0][0]);                                 \
    const unsigned sBb_ = lds_off(&sB[0][0][0][0]);                                 \
    const int ck0_ = quad, ck1_ = 4 + quad;                                         \
    const unsigned aOff0_ = (unsigned)((ck0_ * 256 + (aRow_ ^ (ck0_ << 1))) * 16);  \
    const unsigned aOff1_ = (unsigned)((ck1_ * 256 + (aRow_ ^ (ck1_ << 1))) * 16);  \
    const unsigned bOff0_ = (unsigned)((ck0_ * 256 + (bRow_ ^ (ck0_ << 1))) * 16);  \
    const unsigned bOff1_ = (unsigned)((ck1_ * 256 + (bRow_ ^ (ck1_ << 1))) * 16);

#define GEMM_CORE()                                                                 \
    GEMM_PRELUDE()                                                                  \
    STG_A(0, 0, 0); STG_B(0, 0, 0); STG_A(0, 0, 1); STG_B(0, 0, 1);                 \
    SBAR VMC("4") BARR SBAR                                                         \
    KTILE(0, STG_A(1, 1, 0), STG_B(1, 1, 0), STG_A(1, 1, 1), STG_B(1, 1, 1), "4", VMC("4")) \
    KTILE(1, STG_A(0, 2, 0), STG_B(0, 2, 0), STG_A(0, 2, 1), STG_B(0, 2, 1), "4", VMC("4")) \
    KTILE(0, STG_A(1, 3, 0), STG_B(1, 3, 0), STG_A(1, 3, 1), STG_B(1, 3, 1), "4", VMC("4")) \
    KTILE(1, , , , , "0", )

// wave-aggregated global overflow append
#define CAND_APPEND(e)                                                              \
    do {                                                                            \
        const u64 am_ = __builtin_amdgcn_read_exec();                               \
        const unsigned n_ = (unsigned)__popcll(am_);                                \
        const unsigned rk_ = (unsigned)__popcll(am_ & ((1ull << lane) - 1));        \
        unsigned base_ = 0;                                                         \
        if (rk_ == 0) base_ = atomicAdd(cnt, n_);                                   \
        base_ = (unsigned)__builtin_amdgcn_readfirstlane((int)base_);               \
        const unsigned g_ = base_ + rk_;                                            \
        if (g_ < cap) cand[g_] = (e);                                               \
    } while (0)

// XCD-chunked bijective decode (1-D grid, xcd = bid & 7)
#define XCD_DECODE(NT0)                                                             \
    const unsigned bid_ = blockIdx.x;                                               \
    const unsigned j_ = bid_ >> 3;                                                  \
    const int m0 = (int)(((bid_ & 7u) << 2) | (j_ & 3u)) * 256;                     \
    const int n0 = (NT0) + (int)(j_ >> 2) * 256;

// ---- phase 1: codes [0,2048). Self-seeded thresholds; publishes block max at exit. ----
__global__ __launch_bounds__(512, 2) void score_seed(const unsigned short* __restrict__ zfbT,
                                                     const unsigned short* __restrict__ ewbT,
                                                     unsigned* __restrict__ gmax,
                                                     u64* __restrict__ cand,
                                                     unsigned* __restrict__ cnt,
                                                     unsigned cap) {
    __shared__ unsigned thrS[256];
    __shared__ u64 lbuf[LCAP];
    __shared__ unsigned lcount, lbase;

    const int tid = threadIdx.x, lane = tid & 63, wave = tid >> 6;
    const int quad = lane >> 4, col = lane & 15;
    const int wm = wave >> 2, wn = wave & 3;
    XCD_DECODE(0)
    const int shsrc = lane & 48;

    if (tid < 256) thrS[tid] = 0u;
    if (tid == 0) lcount = 0u;

    GEMM_CORE()
    __syncthreads();   // all waves done with GEMM; publish thrS/lcount init before epilogue

    float red[8][4];
    #pragma unroll
    for (int mt = 0; mt < 8; ++mt)
        #pragma unroll
        for (int r = 0; r < 4; ++r)
            red[mt][r] = fmaxf(fmaxf(acc[mt][0][r], acc[mt][1][r]),
                               fmaxf(acc[mt][2][r], acc[mt][3][r]));
    #pragma unroll
    for (int off = 1; off < 16; off <<= 1)
        #pragma unroll
        for (int mt = 0; mt < 8; ++mt)
            #pragma unroll
            for (int r = 0; r < 4; ++r)
                red[mt][r] = fmaxf(red[mt][r], __shfl_xor(red[mt][r], off));
    #pragma unroll
    for (int mt = 0; mt < 8; ++mt)
        #pragma unroll
        for (int r = 0; r < 4; ++r) {
            const int pl = wm * 128 + mt * 16 + quad * 4 + r;
            unsigned cur = 0;
            if (col == 0) {
                const unsigned enc = f2s(red[mt][r]);
                const unsigned old = atomicMax(&thrS[pl], enc);
                cur = old > enc ? old : enc;
            }
            cur = (unsigned)__shfl((int)cur, shsrc);
            red[mt][r] = s2f(cur) - DELTA;
        }

    const int ncode0 = n0 + wn * 64 + col;
    #pragma unroll
    for (int mt = 0; mt < 8; ++mt) {
        #pragma unroll
        for (int r = 0; r < 4; ++r) {
            const float tp = red[mt][r];
            const unsigned pt = m0 + wm * 128 + mt * 16 + quad * 4 + r;
            #pragma unroll
            for (int nt = 0; nt < 4; ++nt) {
                const float v = acc[mt][nt][r];
                if (v >= tp) {
                    const unsigned slot = atomicAdd(&lcount, 1u);
                    const u64 e = ((u64)((pt << 14) | (unsigned)(ncode0 + nt * 16)) << 32)
                                  | f2s(v);
                    if (slot < LCAP) lbuf[slot] = e;
                    else CAND_APPEND(e);
                }
            }
        }
    }

    __syncthreads();
    if (tid < 256) atomicMax(&gmax[m0 + tid], thrS[tid]);
    const unsigned m_ = lcount < LCAP ? lcount : LCAP;
    if (tid == 0) lbase = atomicAdd(cnt, m_);
    __syncthreads();
    for (unsigned i = tid; i < m_; i += 512) {
        const unsigned g = lbase + i;
        if (g < cap) cand[g] = lbuf[i];
    }
}

// ---- phase 2: codes [2048,16384). Static thresholds from gmax. ----
__global__ __launch_bounds__(512, 2) void score_main(const unsigned short* __restrict__ zfbT,
                                                     const unsigned short* __restrict__ ewbT,
                                                     const unsigned* __restrict__ gmax,
                                                     u64* __restrict__ cand,
                                                     unsigned* __restrict__ cnt,
                                                     unsigned cap) {
    __shared__ float thrL[256];
    __shared__ u64 lbuf[LCAP];
    __shared__ unsigned lcount, lbase;

    const int tid = threadIdx.x, lane = tid & 63, wave = tid >> 6;
    const int quad = lane >> 4, col = lane & 15;
    const int wm = wave >> 2, wn = wave & 3;
    XCD_DECODE(2048)

    if (tid < 256) thrL[tid] = s2f(gmax[m0 + tid]) - DELTA;
    if (tid == 0) lcount = 0u;

    GEMM_CORE()
    __syncthreads();   // all waves done with GEMM; publish thrL/lcount init before epilogue

    const int ncode0 = n0 + wn * 64 + col;
    #pragma unroll
    for (int mt = 0; mt < 8; ++mt) {
        #pragma unroll
        for (int r = 0; r < 4; ++r) {
            const int pl = wm * 128 + mt * 16 + quad * 4 + r;
            const float tp = thrL[pl];
            #pragma unroll
            for (int nt = 0; nt < 4; ++nt) {
                const float v = acc[mt][nt][r];
                if (v >= tp) {
                    const unsigned slot = atomicAdd(&lcount, 1u);
                    const u64 e = ((u64)(((unsigned)pl + m0) << 14 | (unsigned)(ncode0 + nt * 16)) << 32)
                                  | f2s(v);
                    if (slot < LCAP) lbuf[slot] = e;
                    else CAND_APPEND(e);
                }
            }
        }
    }

    __syncthreads();
    const unsigned m_ = lcount < LCAP ? lcount : LCAP;
    if (tid == 0) lbase = atomicAdd(cnt, m_);
    __syncthreads();
    for (unsigned i = tid; i < m_; i += 512) {
        const unsigned g = lbase + i;
        if (g < cap) cand[g] = lbuf[i];
    }
}

// ================== DIAGNOSTIC PROBES (corrected rep-scaling; this round only) ==================
// Identical geometry/occupancy to score_main. REPS=12 -> every probe lands well above
// score_main (106us) in the top-5. Variants disambiguated by COUNTERS, not name:
//   V1: ds_read+lgkm+MFMA+barriers (FETCH~0, Mfma>0)   -> LDS-path + MFMA cost
//   V5: ds_read+lgkm+barriers      (FETCH~0, Mfma=0)   -> pure LDS-path cost
//   V2: staging+vmcnt+barriers     (FETCH>0, Mfma=0)   -> staging-path cost
//   V7: ALL components, NO mid-rep syncs (racy; FETCH>0, Mfma>0, dur < others)
//       -> pure-throughput union; real minus V7 = total serialization/sync cost
// rule #17: acc kept live via asm sinks; ds_reads/staging are volatile asm (no DCE).
#define PPH(RDOPS, STGOPS, MFOPS, VMCOPS)                                           \
    if constexpr (V == 1 || V == 5) { RDOPS; }                                      \
    if constexpr (V == 2) { STGOPS; }                                               \
    SBAR BARR                                                                       \
    if constexpr (V == 1 || V == 5) { LGKM_SB }                                     \
    if constexpr (V == 1) { MFOPS; }                                                \
    SBAR                                                                            \
    if constexpr (V == 2) { VMCOPS }                                                \
    BARR SBAR

#define P7TILE(s)                                                                   \
    RD_A(s, aOff0_, 0); RD_B(s, bOff0_); MF(0);                                     \
    RD_A(s, aOff0_, 1);                  MF(1);                                     \
    RD_A(s, aOff1_, 0); RD_B(s, bOff1_); MF(0);                                     \
    RD_A(s, aOff1_, 1);                  MF(1);

template<int V>
__global__ __launch_bounds__(512, 2) void probe(const unsigned short* __restrict__ zfbT,
                                                const unsigned short* __restrict__ ewbT) {
    constexpr int REPS = 12;
    const int tid = threadIdx.x, lane = tid & 63, wave = tid >> 6;
    const int quad = lane >> 4, col = lane & 15;
    const int wm = wave >> 2, wn = wave & 3;
    XCD_DECODE(2048)
    (void)lane;

    GEMM_PRELUDE()
    if constexpr (V == 2) {  // MFMA never runs but keep af_/bf_ defined
        #pragma unroll
        for (int j2 = 0; j2 < 4; ++j2) {
            asm volatile("" : "=v"(af_[j2]));
            asm volatile("" : "=v"(bf_[j2]));
        }
    }

    #pragma unroll 1
    for (int rep = 0; rep < REPS; ++rep) {
        if constexpr (V == 7) {
            STG_A(0, 0, 0); STG_B(0, 0, 0); STG_A(0, 0, 1); STG_B(0, 0, 1);
            P7TILE(0)
            STG_A(1, 1, 0); STG_B(1, 1, 0); STG_A(1, 1, 1); STG_B(1, 1, 1);
            P7TILE(1)
            STG_A(0, 2, 0); STG_B(0, 2, 0); STG_A(0, 2, 1); STG_B(0, 2, 1);
            P7TILE(0)
            STG_A(1, 3, 0); STG_B(1, 3, 0); STG_A(1, 3, 1); STG_B(1, 3, 1);
            P7TILE(1)
            VMC("0") asm volatile("s_waitcnt lgkmcnt(0)");
            BARR SBAR
        } else {
            if constexpr (V == 2) {
                STG_A(0, 0, 0); STG_B(0, 0, 0); STG_A(0, 0, 1); STG_B(0, 0, 1);
                SBAR VMC("4") BARR SBAR
            } else {
                BARR
            }
            PPH(RD_A(0, aOff0_, 0); RD_B(0, bOff0_), STG_A(1, 1, 0), MF(0), )
            PPH(RD_A(0, aOff0_, 1),                  STG_B(1, 1, 0), MF(1), VMC("4"))
            PPH(RD_A(0, aOff1_, 0); RD_B(0, bOff1_), STG_A(1, 1, 1), MF(0), )
            PPH(RD_A(0, aOff1_, 1),                  STG_B(1, 1, 1), MF(1), VMC("4"))
            PPH(RD_A(1, aOff0_, 0); RD_B(1, bOff0_), STG_A(0, 2, 0), MF(0), )
            PPH(RD_A(1, aOff0_, 1),                  STG_B(0, 2, 0), MF(1), VMC("4"))
            PPH(RD_A(1, aOff1_, 0); RD_B(1, bOff1_), STG_A(0, 2, 1), MF(0), )
            PPH(RD_A(1, aOff1_, 1),                  STG_B(0, 2, 1), MF(1), VMC("4"))
            PPH(RD_A(0, aOff0_, 0); RD_B(0, bOff0_), STG_A(1, 3, 0), MF(0), )
            PPH(RD_A(0, aOff0_, 1),                  STG_B(1, 3, 0), MF(1), VMC("4"))
            PPH(RD_A(0, aOff1_, 0); RD_B(0, bOff1_), STG_A(1, 3, 1), MF(0), )
            PPH(RD_A(0, aOff1_, 1),                  STG_B(1, 3, 1), MF(1), VMC("4"))
            PPH(RD_A(1, aOff0_, 0); RD_B(1, bOff0_), , MF(0), )
            PPH(RD_A(1, aOff0_, 1),                  , MF(1), VMC("0"))
            PPH(RD_A(1, aOff1_, 0); RD_B(1, bOff1_), , MF(0), )
            PPH(RD_A(1, aOff1_, 1),                  , MF(1), )
        }
    }
    #pragma unroll
    for (int i_ = 0; i_ < 8; ++i_)
        #pragma unroll
        for (int j2 = 0; j2 < 4; ++j2)
            asm volatile("" :: "v"(acc[i_][j2]));
}

// ---- final per-point bf16 max over candidates ----
__global__ __launch_bounds__(256) void cand_max(const u64* __restrict__ cand,
                                                const unsigned* __restrict__ cnt,
                                                unsigned* __restrict__ gmax,
                                                unsigned cap) {
    const unsigned total = min(cnt[0], cap);
    const unsigned stride = gridDim.x * 256;
    for (unsigned i = blockIdx.x * 256 + threadIdx.x; i < total; i += stride) {
        const u64 e = cand[i];
        atomicMax(&gmax[(unsigned)(e >> 46)], (unsigned)(e & 0xffffffffull));
    }
}

// ---- lane-parallel filter + ballot-compacted wave-cooperative fp32 rescore ----
__global__ __launch_bounds__(256) void rescore(const float* __restrict__ zf32,
                                               const float* __restrict__ E,
                                               const float* __restrict__ den,
                                               const unsigned* __restrict__ gmax,
                                               const u64* __restrict__ cand,
                                               const unsigned* __restrict__ cnt,
                                               u64* __restrict__ keys,
                                               unsigned cap) {
    const unsigned total = min(cnt[0], cap);
    const int lane = threadIdx.x & 63;
    const unsigned w = (blockIdx.x * 256 + threadIdx.x) >> 6;
    const unsigned nw = gridDim.x * 4;
    for (unsigned base = w * 64; base < total; base += nw * 64) {
        const unsigned i = base + lane;
        u64 e = 0;
        bool keep = false;
        if (i < total) {
            e = cand[i];
            const int p = (int)(e >> 46);
            keep = (s2f((unsigned)(e & 0xffffffffull)) >= s2f(gmax[p]) - DELTA);
        }
        u64 mask = __ballot(keep);
        while (mask) {
            const int src = __ffsll((long long)mask) - 1;
            mask &= mask - 1;
            const unsigned pc = (unsigned)__shfl((int)(unsigned)(e >> 32), src);
            const int p = pc >> 14, c = pc & 16383;
            const float dinv = 1.0f / den[c];
            const float4 a = *(const float4*)(zf32 + (size_t)p * D + lane * 4);
            const float4 b = *(const float4*)(E + (size_t)c * D + lane * 4);
            float sv = fmaf(a.x, b.x * dinv, fmaf(a.y, b.y * dinv,
                       fmaf(a.z, b.z * dinv, a.w * (b.w * dinv))));
            #pragma unroll
            for (int o = 1; o < 64; o <<= 1) sv += __shfl_xor(sv, o);
            if (lane == 0)
                atomicMax(keys + p, ((u64)f2s(sv) << 32) | (unsigned)(16383 - c));
        }
    }
}

// ---- gather + outputs (LDS transpose for coalesced zq writes) ----
__global__ __launch_bounds__(256) void finalize(const float* __restrict__ E,
                                                const float* __restrict__ den,
                                                const u64* __restrict__ keys,
                                                float* __restrict__ out) {
    __shared__ float t[32][257];
    __shared__ int sIdx[32];
    __shared__ float sDen[32];
    const int tid = threadIdx.x;
    const int n0 = blockIdx.x * 32;
    if (tid < 32) {
        const u64 key = keys[n0 + tid];
        const int idx = 16383 - (int)(unsigned)(key & 0xffffffffull);
        sIdx[tid] = idx;
        sDen[tid] = den[idx];
        out[O_IDX + n0 + tid] = (float)idx;
    }
    __syncthreads();
    const float S = 5.65685424949238019520675489683895f;  // sqrt(32)
    #pragma unroll 4
    for (int i = 0; i < 32; ++i) {
        const float v = E[(size_t)sIdx[i] * D + tid] / sDen[i];
        t[i][tid] = v;
        out[O_BIT + (size_t)(n0 + i) * D + tid] = (float)((int)(v * S) + 4);
    }
    __syncthreads();
    const int b = n0 >> 10, hw0 = n0 & 1023;
    const int hwl = tid & 31, cg = tid >> 5;
    #pragma unroll 4
    for (int cc = 0; cc < 32; ++cc) {
        const int c = cc * 8 + cg;
        out[(size_t)(b * 256 + c) * 1024 + hw0 + hwl] = t[hwl][c];
    }
    if (n0 == 0 && tid == 0) out[O_LOSS] = 0.0f;
}

extern "C" void kernel_launch(void* const* d_in, const int* in_sizes, int n_in,
                              void* d_out, int out_size, void* d_ws, size_t ws_size,
                              hipStream_t stream) {
    const float* z = (const float*)d_in[0];
    const float* E = (const float*)d_in[1];
    float* out = (float*)d_out;

    char* w = (char*)d_ws;
    unsigned short* ewbT = (unsigned short*)w;  w += (size_t)K * D * 2;      //  8 MB
    unsigned short* zfbT = (unsigned short*)w;  w += (size_t)NPTS * D * 2;   //  4 MB
    float*          zf32 = (float*)w;           w += (size_t)NPTS * D * 4;   //  8 MB
    u64*            keys = (u64*)w;             w += (size_t)NPTS * 8;       // 64 KB
    float*          den  = (float*)w;           w += (size_t)K * 4;          // 64 KB
    unsigned*       gmax = (unsigned*)w;        w += (size_t)NPTS * 4;       // 32 KB
    unsigned*       cnt  = (unsigned*)w;        w += 256;
    u64*            cand = (u64*)w;             // remainder of ws
    const size_t fixed = (size_t)(w - (char*)d_ws);
    const size_t avail = ws_size > fixed ? (ws_size - fixed) / 8 : 0;
    const unsigned cap = (unsigned)(avail < (size_t)MAXCAP ? avail : (size_t)MAXCAP);

    prep<<<640, 256, 0, stream>>>(E, z, den, ewbT, zfbT, zf32, gmax, keys, cnt);

    score_seed<<<256, 512, 0, stream>>>(zfbT, ewbT, gmax, cand, cnt, cap);
    score_main<<<1792, 512, 0, stream>>>(zfbT, ewbT, gmax, cand, cnt, cap);

    cand_max<<<256, 256, 0, stream>>>(cand, cnt, gmax, cap);
    rescore<<<1024, 256, 0, stream>>>(zf32, E, den, gmax, cand, cnt, keys, cap);
    finalize<<<NPTS / 32, 256, 0, stream>>>(E, den, keys, out);

    // ---- diagnostic probes (outputs already written; timing cost this round only) ----
    probe<1><<<1792, 512, 0, stream>>>(zfbT, ewbT);
    probe<5><<<1792, 512, 0, stream>>>(zfbT, ewbT);
    probe<2><<<1792, 512, 0, stream>>>(zfbT, ewbT);
    probe<7><<<1792, 512, 0, stream>>>(zfbT, ewbT);
}

// Round 11
// 336.850 us; speedup vs baseline: 4.3712x; 4.3712x over previous
//
#include <hip/hip_runtime.h>
#include <math.h>

#define D      256
#define K      16384
#define NPTS   8192
#define DELTA  0.2f
#define LCAP   1024
#define MAXCAP 4000000u

// d_out layout (all f32): zq[8,256,32,32] | indices[8192] | bit[8,32,32,256] | loss[1]
#define O_IDX  2097152
#define O_BIT  2105344
#define O_LOSS 4202496

typedef __attribute__((ext_vector_type(8))) short bf16x8;
typedef __attribute__((ext_vector_type(4))) float f32x4;
typedef unsigned long long u64;

__device__ __forceinline__ unsigned f2s(float f) {
    unsigned u = __float_as_uint(f);
    return (u & 0x80000000u) ? ~u : (u | 0x80000000u);
}
__device__ __forceinline__ float s2f(unsigned s) {
    return __uint_as_float((s & 0x80000000u) ? (s & 0x7fffffffu) : ~s);
}
__device__ __forceinline__ unsigned short f2bf(float f) {  // RNE
    unsigned u = __float_as_uint(f);
    u += 0x7fffu + ((u >> 16) & 1u);
    return (unsigned short)(u >> 16);
}

// async global->LDS, 16B per lane (wave-uniform base + lane*16 dest)
__device__ __forceinline__ void gload16(const unsigned short* g, unsigned short* l) {
    __builtin_amdgcn_global_load_lds(
        (const __attribute__((address_space(1))) unsigned int*)g,
        (__attribute__((address_space(3))) unsigned int*)l, 16, 0, 0);
}

// k-major fragment layouts: X[(k>>3)][row][8] bf16, 16B per (row, k-chunk)
//   zfbT: [32][NPTS][8] bf16 ; ewbT: [32][K][8] bf16

// ---- merged prep: blocks [0,512) codebook; [512,640) z transpose; state init folded ----
__global__ __launch_bounds__(256) void prep(const float* __restrict__ E,
                                            const float* __restrict__ z,
                                            float* __restrict__ den,
                                            unsigned short* __restrict__ ewbT,
                                            unsigned short* __restrict__ zfbT,
                                            float* __restrict__ zf32,
                                            unsigned* __restrict__ gmax,
                                            u64* __restrict__ keys,
                                            unsigned* __restrict__ cnt) {
    const int blk = blockIdx.x, tid = threadIdx.x;
    if (blk < 512) {
        const int lane = tid & 63, wave = tid >> 6;
        if (blk < 32)        gmax[blk * 256 + tid] = 0u;
        else if (blk < 64)   keys[(blk - 32) * 256 + tid] = 0ull;
        else if (blk == 64 && tid < 2) cnt[tid] = 0u;
        #pragma unroll
        for (int j = 0; j < 8; ++j) {
            const int row = blk * 32 + wave * 8 + j;
            const float4 v = *(const float4*)(E + (size_t)row * D + lane * 4);
            float ss = v.x * v.x + v.y * v.y + v.z * v.z + v.w * v.w;
            #pragma unroll
            for (int o = 1; o < 64; o <<= 1) ss += __shfl_xor(ss, o);
            const float dn = fmaxf(sqrtf(ss), 1e-12f);
            const unsigned lo = (unsigned)f2bf(v.x / dn) | ((unsigned)f2bf(v.y / dn) << 16);
            const unsigned hi = (unsigned)f2bf(v.z / dn) | ((unsigned)f2bf(v.w / dn) << 16);
            // k = lane*4 .. +4 -> chunk lane>>1, offset (lane&1)*4
            *(uint2*)(ewbT + ((size_t)(lane >> 1) * K + row) * 8 + (lane & 1) * 4)
                = make_uint2(lo, hi);
            if (lane == 0) den[row] = dn;
        }
    } else {
        const int bi = blk - 512;
        const int b = bi >> 4, hw0 = (bi & 15) * 64;
        __shared__ float t[64][65];
        for (int dc = 0; dc < D; dc += 64) {
            #pragma unroll
            for (int it = 0; it < 16; ++it) {
                const int idx = it * 256 + tid;
                const int dl = idx >> 6, hw = idx & 63;
                t[dl][hw] = z[(size_t)(b * 256 + dc + dl) * 1024 + hw0 + hw];
            }
            __syncthreads();
            // zf32: coalesced f32 writes
            #pragma unroll
            for (int it = 0; it < 16; ++it) {
                const int idx = it * 256 + tid;
                const int pl = idx >> 6, dl = idx & 63;
                zf32[(size_t)(b * 1024 + hw0 + pl) * D + dc + dl] = t[dl][pl];
            }
            // zfbT: vectorized 16B coalesced stores
            #pragma unroll
            for (int tk = 0; tk < 2; ++tk) {
                const int task = tk * 256 + tid;
                const int ch = task >> 6, pl = task & 63;
                const int p = b * 1024 + hw0 + pl;
                unsigned short u[8];
                #pragma unroll
                for (int j = 0; j < 8; ++j) u[j] = f2bf(t[ch * 8 + j][pl]);
                *(uint4*)(zfbT + ((size_t)((dc >> 3) + ch) * NPTS + p) * 8) = *(uint4*)u;
            }
            __syncthreads();
        }
    }
}

// ================= all-K-resident GEMM core (round 11) =================
// r8/r10 ablation: every component (ds-path, staging, MFMA, barriers) runs at 4-6us/block
// ALONE, and the no-sync union (probe V7) also runs at ~6us -- hardware overlaps them fine.
// The real core's 14us came from per-phase waits serializing the staging stream against
// the ds/MFMA stream. K=256 is small enough that a 128x128 tile's ENTIRE K fits LDS
// (64KB A + 64KB B), so: stage everything once (32 gload16), ONE __syncthreads (single
// vmcnt(0) drain, paid once with all 32 loads pipelined), then a pure C-level compute
// loop -- no barriers, no asm, no outstanding LDS-DMA -> compiler's fine-grained lgkm
// scheduling applies and conservative vmcnt(0) inserts are free (counter already 0).
// 256 threads = 4 waves (2x2), per-wave 64x64 out, acc[4][4] -- identical wave/epilogue
// geometry to the verified r0-r4 kernels. XOR swizzle (row ^ (quad<<1)) on the global
// side, undone on the read side -- 0 bank conflicts all session.

#define STAGE_ALL()                                                                 \
    _Pragma("unroll")                                                               \
    for (int g_ = 0; g_ < 8; ++g_) {                                                \
        { const int c_ = 4 * g_ + hi_;                                              \
          gload16(zfbT + ((size_t)c_ * NPTS + m0 + (th_ ^ ((c_ & 3) << 1))) * 8,    \
                  &sA[c_][th_][0]); }                                               \
        { const int c_ = 4 * g_ + 2 + hi_;                                          \
          gload16(zfbT + ((size_t)c_ * NPTS + m0 + (th_ ^ ((c_ & 3) << 1))) * 8,    \
                  &sA[c_][th_][0]); }                                               \
        { const int c_ = 4 * g_ + hi_;                                              \
          gload16(ewbT + ((size_t)c_ * K + n0 + (th_ ^ ((c_ & 3) << 1))) * 8,       \
                  &sB[c_][th_][0]); }                                               \
        { const int c_ = 4 * g_ + 2 + hi_;                                          \
          gload16(ewbT + ((size_t)c_ * K + n0 + (th_ ^ ((c_ & 3) << 1))) * 8,       \
                  &sB[c_][th_][0]); }                                               \
    }

#define GEMM_CORE()                                                                 \
    f32x4 acc[4][4];                                                                \
    _Pragma("unroll")                                                               \
    for (int i_ = 0; i_ < 4; ++i_)                                                  \
        _Pragma("unroll")                                                           \
        for (int j_ = 0; j_ < 4; ++j_) acc[i_][j_] = (f32x4){0.f, 0.f, 0.f, 0.f};   \
    {                                                                               \
        const int th_ = tid & 127, hi_ = tid >> 7;                                  \
        STAGE_ALL()                                                                 \
    }                                                                               \
    __syncthreads();  /* single vmcnt(0) drain + publishes thr/lcount init */       \
    {                                                                               \
        const int rA_ = (wm * 64 + col) ^ (quad << 1);                              \
        const int rB_ = (wn * 64 + col) ^ (quad << 1);                              \
        _Pragma("unroll")                                                           \
        for (int dc_ = 0; dc_ < 8; ++dc_) {                                         \
            const unsigned short* pa_ = &sA[4 * dc_ + quad][rA_][0];                \
            const unsigned short* pb_ = &sB[4 * dc_ + quad][rB_][0];                \
            bf16x8 af_[4], bf_[4];                                                  \
            _Pragma("unroll")                                                       \
            for (int mt_ = 0; mt_ < 4; ++mt_) {                                     \
                af_[mt_] = *(const bf16x8*)(pa_ + mt_ * 128);                       \
                bf_[mt_] = *(const bf16x8*)(pb_ + mt_ * 128);                       \
            }                                                                       \
            _Pragma("unroll")                                                       \
            for (int mt_ = 0; mt_ < 4; ++mt_)                                       \
                _Pragma("unroll")                                                   \
                for (int nt_ = 0; nt_ < 4; ++nt_)                                   \
                    acc[mt_][nt_] = __builtin_amdgcn_mfma_f32_16x16x32_bf16(        \
                        af_[mt_], bf_[nt_], acc[mt_][nt_], 0, 0, 0);                \
        }                                                                           \
    }

// wave-aggregated global overflow append (round-3 lesson: per-candidate same-address
// atomics serialize catastrophically)
#define CAND_APPEND(e)                                                              \
    do {                                                                            \
        const u64 am_ = __builtin_amdgcn_read_exec();                               \
        const unsigned n_ = (unsigned)__popcll(am_);                                \
        const unsigned rk_ = (unsigned)__popcll(am_ & ((1ull << lane) - 1));        \
        unsigned base_ = 0;                                                         \
        if (rk_ == 0) base_ = atomicAdd(cnt, n_);                                   \
        base_ = (unsigned)__builtin_amdgcn_readfirstlane((int)base_);               \
        const unsigned g_ = base_ + rk_;                                            \
        if (g_ < cap) cand[g_] = (e);                                               \
    } while (0)

// XCD-chunked bijective decode (1-D grid, xcd = bid & 7). XCD k owns m-tiles [8k, 8k+8):
// per-XCD zfbT footprint 512 KB (L2-resident); n-slices walked slowly so each 64 KB ewbT
// slice is L2-shared by the ~8 co-resident m-blocks on that XCD.
#define XCD_DECODE(NT0)                                                             \
    const unsigned bid_ = blockIdx.x;                                               \
    const unsigned j_ = bid_ >> 3;                                                  \
    const int m0 = (int)(((bid_ & 7u) << 3) | (j_ & 7u)) * 128;                     \
    const int n0 = ((NT0) + (int)(j_ >> 3)) * 128;

// ---- phase 1: slices [0,16). Self-seeded thresholds; publishes block max at exit. ----
__global__ __launch_bounds__(256, 1) void score_seed(const unsigned short* __restrict__ zfbT,
                                                     const unsigned short* __restrict__ ewbT,
                                                     unsigned* __restrict__ gmax,
                                                     u64* __restrict__ cand,
                                                     unsigned* __restrict__ cnt,
                                                     unsigned cap) {
    __shared__ unsigned short sA[32][128][8];
    __shared__ unsigned short sB[32][128][8];
    __shared__ unsigned thrS[128];
    __shared__ u64 lbuf[LCAP];
    __shared__ unsigned lcount, lbase;

    const int tid = threadIdx.x, lane = tid & 63, wave = tid >> 6;
    const int quad = lane >> 4, col = lane & 15;
    const int wm = wave >> 1, wn = wave & 1;
    XCD_DECODE(0)
    const int shsrc = lane & 48;

    if (tid < 128) thrS[tid] = 0u;
    if (tid == 0) lcount = 0u;

    GEMM_CORE()

    float red[4][4];
    #pragma unroll
    for (int mt = 0; mt < 4; ++mt)
        #pragma unroll
        for (int r = 0; r < 4; ++r)
            red[mt][r] = fmaxf(fmaxf(acc[mt][0][r], acc[mt][1][r]),
                               fmaxf(acc[mt][2][r], acc[mt][3][r]));
    #pragma unroll
    for (int off = 1; off < 16; off <<= 1)
        #pragma unroll
        for (int mt = 0; mt < 4; ++mt)
            #pragma unroll
            for (int r = 0; r < 4; ++r)
                red[mt][r] = fmaxf(red[mt][r], __shfl_xor(red[mt][r], off));
    #pragma unroll
    for (int mt = 0; mt < 4; ++mt)
        #pragma unroll
        for (int r = 0; r < 4; ++r) {
            const int pl = wm * 64 + mt * 16 + quad * 4 + r;
            unsigned cur = 0;
            if (col == 0) {
                const unsigned enc = f2s(red[mt][r]);
                const unsigned old = atomicMax(&thrS[pl], enc);
                cur = old > enc ? old : enc;
            }
            cur = (unsigned)__shfl((int)cur, shsrc);
            red[mt][r] = s2f(cur) - DELTA;
        }

    const int ncode0 = n0 + wn * 64 + col;
    #pragma unroll
    for (int mt = 0; mt < 4; ++mt) {
        #pragma unroll
        for (int r = 0; r < 4; ++r) {
            const float tp = red[mt][r];
            const unsigned pt = m0 + wm * 64 + mt * 16 + quad * 4 + r;
            #pragma unroll
            for (int nt = 0; nt < 4; ++nt) {
                const float v = acc[mt][nt][r];
                if (v >= tp) {
                    const unsigned slot = atomicAdd(&lcount, 1u);
                    const u64 e = ((u64)((pt << 14) | (unsigned)(ncode0 + nt * 16)) << 32)
                                  | f2s(v);
                    if (slot < LCAP) lbuf[slot] = e;
                    else CAND_APPEND(e);
                }
            }
        }
    }

    __syncthreads();
    if (tid < 128) atomicMax(&gmax[m0 + tid], thrS[tid]);
    const unsigned m_ = lcount < LCAP ? lcount : LCAP;
    if (tid == 0) lbase = atomicAdd(cnt, m_);
    __syncthreads();
    for (unsigned i = tid; i < m_; i += 256) {
        const unsigned g = lbase + i;
        if (g < cap) cand[g] = lbuf[i];
    }
}

// ---- phase 2: slices [16,128). Static thresholds from gmax. ----
__global__ __launch_bounds__(256, 1) void score_main(const unsigned short* __restrict__ zfbT,
                                                     const unsigned short* __restrict__ ewbT,
                                                     const unsigned* __restrict__ gmax,
                                                     u64* __restrict__ cand,
                                                     unsigned* __restrict__ cnt,
                                                     unsigned cap) {
    __shared__ unsigned short sA[32][128][8];
    __shared__ unsigned short sB[32][128][8];
    __shared__ float thrL[128];
    __shared__ u64 lbuf[LCAP];
    __shared__ unsigned lcount, lbase;

    const int tid = threadIdx.x, lane = tid & 63, wave = tid >> 6;
    const int quad = lane >> 4, col = lane & 15;
    const int wm = wave >> 1, wn = wave & 1;
    XCD_DECODE(16)

    if (tid < 128) thrL[tid] = s2f(gmax[m0 + tid]) - DELTA;
    if (tid == 0) lcount = 0u;

    GEMM_CORE()

    const int ncode0 = n0 + wn * 64 + col;
    #pragma unroll
    for (int mt = 0; mt < 4; ++mt) {
        #pragma unroll
        for (int r = 0; r < 4; ++r) {
            const int pl = wm * 64 + mt * 16 + quad * 4 + r;
            const float tp = thrL[pl];
            #pragma unroll
            for (int nt = 0; nt < 4; ++nt) {
                const float v = acc[mt][nt][r];
                if (v >= tp) {
                    const unsigned slot = atomicAdd(&lcount, 1u);
                    const u64 e = ((u64)(((unsigned)pl + m0) << 14 | (unsigned)(ncode0 + nt * 16)) << 32)
                                  | f2s(v);
                    if (slot < LCAP) lbuf[slot] = e;
                    else CAND_APPEND(e);
                }
            }
        }
    }

    __syncthreads();
    const unsigned m_ = lcount < LCAP ? lcount : LCAP;
    if (tid == 0) lbase = atomicAdd(cnt, m_);
    __syncthreads();
    for (unsigned i = tid; i < m_; i += 256) {
        const unsigned g = lbase + i;
        if (g < cap) cand[g] = lbuf[i];
    }
}

// ---- final per-point bf16 max over candidates ----
__global__ __launch_bounds__(256) void cand_max(const u64* __restrict__ cand,
                                                const unsigned* __restrict__ cnt,
                                                unsigned* __restrict__ gmax,
                                                unsigned cap) {
    const unsigned total = min(cnt[0], cap);
    const unsigned stride = gridDim.x * 256;
    for (unsigned i = blockIdx.x * 256 + threadIdx.x; i < total; i += stride) {
        const u64 e = cand[i];
        atomicMax(&gmax[(unsigned)(e >> 46)], (unsigned)(e & 0xffffffffull));
    }
}

// ---- lane-parallel filter + ballot-compacted wave-cooperative fp32 rescore ----
__global__ __launch_bounds__(256) void rescore(const float* __restrict__ zf32,
                                               const float* __restrict__ E,
                                               const float* __restrict__ den,
                                               const unsigned* __restrict__ gmax,
                                               const u64* __restrict__ cand,
                                               const unsigned* __restrict__ cnt,
                                               u64* __restrict__ keys,
                                               unsigned cap) {
    const unsigned total = min(cnt[0], cap);
    const int lane = threadIdx.x & 63;
    const unsigned w = (blockIdx.x * 256 + threadIdx.x) >> 6;
    const unsigned nw = gridDim.x * 4;
    for (unsigned base = w * 64; base < total; base += nw * 64) {
        const unsigned i = base + lane;
        u64 e = 0;
        bool keep = false;
        if (i < total) {
            e = cand[i];
            const int p = (int)(e >> 46);
            keep = (s2f((unsigned)(e & 0xffffffffull)) >= s2f(gmax[p]) - DELTA);
        }
        u64 mask = __ballot(keep);
        while (mask) {
            const int src = __ffsll((long long)mask) - 1;
            mask &= mask - 1;
            const unsigned pc = (unsigned)__shfl((int)(unsigned)(e >> 32), src);
            const int p = pc >> 14, c = pc & 16383;
            const float dinv = 1.0f / den[c];
            const float4 a = *(const float4*)(zf32 + (size_t)p * D + lane * 4);
            const float4 b = *(const float4*)(E + (size_t)c * D + lane * 4);
            float sv = fmaf(a.x, b.x * dinv, fmaf(a.y, b.y * dinv,
                       fmaf(a.z, b.z * dinv, a.w * (b.w * dinv))));
            #pragma unroll
            for (int o = 1; o < 64; o <<= 1) sv += __shfl_xor(sv, o);
            if (lane == 0)
                atomicMax(keys + p, ((u64)f2s(sv) << 32) | (unsigned)(16383 - c));
        }
    }
}

// ---- gather + outputs (LDS transpose for coalesced zq writes) ----
__global__ __launch_bounds__(256) void finalize(const float* __restrict__ E,
                                                const float* __restrict__ den,
                                                const u64* __restrict__ keys,
                                                float* __restrict__ out) {
    __shared__ float t[32][257];
    __shared__ int sIdx[32];
    __shared__ float sDen[32];
    const int tid = threadIdx.x;
    const int n0 = blockIdx.x * 32;
    if (tid < 32) {
        const u64 key = keys[n0 + tid];
        const int idx = 16383 - (int)(unsigned)(key & 0xffffffffull);
        sIdx[tid] = idx;
        sDen[tid] = den[idx];
        out[O_IDX + n0 + tid] = (float)idx;
    }
    __syncthreads();
    const float S = 5.65685424949238019520675489683895f;  // sqrt(32)
    #pragma unroll 4
    for (int i = 0; i < 32; ++i) {
        const float v = E[(size_t)sIdx[i] * D + tid] / sDen[i];
        t[i][tid] = v;
        out[O_BIT + (size_t)(n0 + i) * D + tid] = (float)((int)(v * S) + 4);
    }
    __syncthreads();
    const int b = n0 >> 10, hw0 = n0 & 1023;
    const int hwl = tid & 31, cg = tid >> 5;
    #pragma unroll 4
    for (int cc = 0; cc < 32; ++cc) {
        const int c = cc * 8 + cg;
        out[(size_t)(b * 256 + c) * 1024 + hw0 + hwl] = t[hwl][c];
    }
    if (n0 == 0 && tid == 0) out[O_LOSS] = 0.0f;
}

extern "C" void kernel_launch(void* const* d_in, const int* in_sizes, int n_in,
                              void* d_out, int out_size, void* d_ws, size_t ws_size,
                              hipStream_t stream) {
    const float* z = (const float*)d_in[0];
    const float* E = (const float*)d_in[1];
    float* out = (float*)d_out;

    char* w = (char*)d_ws;
    unsigned short* ewbT = (unsigned short*)w;  w += (size_t)K * D * 2;      //  8 MB
    unsigned short* zfbT = (unsigned short*)w;  w += (size_t)NPTS * D * 2;   //  4 MB
    float*          zf32 = (float*)w;           w += (size_t)NPTS * D * 4;   //  8 MB
    u64*            keys = (u64*)w;             w += (size_t)NPTS * 8;       // 64 KB
    float*          den  = (float*)w;           w += (size_t)K * 4;          // 64 KB
    unsigned*       gmax = (unsigned*)w;        w += (size_t)NPTS * 4;       // 32 KB
    unsigned*       cnt  = (unsigned*)w;        w += 256;
    u64*            cand = (u64*)w;             // remainder of ws
    const size_t fixed = (size_t)(w - (char*)d_ws);
    const size_t avail = ws_size > fixed ? (ws_size - fixed) / 8 : 0;
    const unsigned cap = (unsigned)(avail < (size_t)MAXCAP ? avail : (size_t)MAXCAP);

    prep<<<640, 256, 0, stream>>>(E, z, den, ewbT, zfbT, zf32, gmax, keys, cnt);

    score_seed<<<1024, 256, 0, stream>>>(zfbT, ewbT, gmax, cand, cnt, cap);
    score_main<<<7168, 256, 0, stream>>>(zfbT, ewbT, gmax, cand, cnt, cap);

    cand_max<<<256, 256, 0, stream>>>(cand, cnt, gmax, cap);
    rescore<<<1024, 256, 0, stream>>>(zf32, E, den, gmax, cand, cnt, keys, cap);
    finalize<<<NPTS / 32, 256, 0, stream>>>(E, den, keys, out);
}

// Round 12
// 234.417 us; speedup vs baseline: 6.2813x; 1.4370x over previous
//
#include <hip/hip_runtime.h>
#include <math.h>

#define D      256
#define K      16384
#define NPTS   8192
#define DELTA  0.2f
#define LCAP   2048
#define MAXCAP 4000000u

// d_out layout (all f32): zq[8,256,32,32] | indices[8192] | bit[8,32,32,256] | loss[1]
#define O_IDX  2097152
#define O_BIT  2105344
#define O_LOSS 4202496

typedef __attribute__((ext_vector_type(8))) short bf16x8;
typedef __attribute__((ext_vector_type(4))) float f32x4;
typedef unsigned long long u64;

__device__ __forceinline__ unsigned f2s(float f) {
    unsigned u = __float_as_uint(f);
    return (u & 0x80000000u) ? ~u : (u | 0x80000000u);
}
__device__ __forceinline__ float s2f(unsigned s) {
    return __uint_as_float((s & 0x80000000u) ? (s & 0x7fffffffu) : ~s);
}
__device__ __forceinline__ unsigned short f2bf(float f) {  // RNE
    unsigned u = __float_as_uint(f);
    u += 0x7fffu + ((u >> 16) & 1u);
    return (unsigned short)(u >> 16);
}

// async global->LDS, 16B per lane (wave-uniform base + lane*16 dest)
__device__ __forceinline__ void gload16(const unsigned short* g, unsigned short* l) {
    __builtin_amdgcn_global_load_lds(
        (const __attribute__((address_space(1))) unsigned int*)g,
        (__attribute__((address_space(3))) unsigned int*)l, 16, 0, 0);
}

// generic LDS pointer -> 32-bit LDS byte offset for inline-asm ds_read
__device__ __forceinline__ unsigned lds_off(const void* p) {
    return (unsigned)(size_t)(const __attribute__((address_space(3))) void*)p;
}

// k-major fragment layouts: X[(k>>3)][row][8] bf16, 16B per (row, k-chunk)
//   zfbT: [32][NPTS][8] bf16 ; ewbT: [32][K][8] bf16

// ---- merged prep: blocks [0,512) codebook; [512,640) z transpose; state init folded ----
__global__ __launch_bounds__(256) void prep(const float* __restrict__ E,
                                            const float* __restrict__ z,
                                            float* __restrict__ den,
                                            unsigned short* __restrict__ ewbT,
                                            unsigned short* __restrict__ zfbT,
                                            float* __restrict__ zf32,
                                            unsigned* __restrict__ gmax,
                                            u64* __restrict__ keys,
                                            unsigned* __restrict__ cnt) {
    const int blk = blockIdx.x, tid = threadIdx.x;
    if (blk < 512) {
        const int lane = tid & 63, wave = tid >> 6;
        if (blk < 32)        gmax[blk * 256 + tid] = 0u;
        else if (blk < 64)   keys[(blk - 32) * 256 + tid] = 0ull;
        else if (blk == 64 && tid < 2) cnt[tid] = 0u;
        #pragma unroll
        for (int j = 0; j < 8; ++j) {
            const int row = blk * 32 + wave * 8 + j;
            const float4 v = *(const float4*)(E + (size_t)row * D + lane * 4);
            float ss = v.x * v.x + v.y * v.y + v.z * v.z + v.w * v.w;
            #pragma unroll
            for (int o = 1; o < 64; o <<= 1) ss += __shfl_xor(ss, o);
            const float dn = fmaxf(sqrtf(ss), 1e-12f);
            const unsigned lo = (unsigned)f2bf(v.x / dn) | ((unsigned)f2bf(v.y / dn) << 16);
            const unsigned hi = (unsigned)f2bf(v.z / dn) | ((unsigned)f2bf(v.w / dn) << 16);
            // k = lane*4 .. +4 -> chunk lane>>1, offset (lane&1)*4
            *(uint2*)(ewbT + ((size_t)(lane >> 1) * K + row) * 8 + (lane & 1) * 4)
                = make_uint2(lo, hi);
            if (lane == 0) den[row] = dn;
        }
    } else {
        const int bi = blk - 512;
        const int b = bi >> 4, hw0 = (bi & 15) * 64;
        __shared__ float t[64][65];
        for (int dc = 0; dc < D; dc += 64) {
            #pragma unroll
            for (int it = 0; it < 16; ++it) {
                const int idx = it * 256 + tid;
                const int dl = idx >> 6, hw = idx & 63;
                t[dl][hw] = z[(size_t)(b * 256 + dc + dl) * 1024 + hw0 + hw];
            }
            __syncthreads();
            // zf32: coalesced f32 writes
            #pragma unroll
            for (int it = 0; it < 16; ++it) {
                const int idx = it * 256 + tid;
                const int pl = idx >> 6, dl = idx & 63;
                zf32[(size_t)(b * 1024 + hw0 + pl) * D + dc + dl] = t[dl][pl];
            }
            // zfbT: vectorized 16B coalesced stores
            #pragma unroll
            for (int tk = 0; tk < 2; ++tk) {
                const int task = tk * 256 + tid;
                const int ch = task >> 6, pl = task & 63;
                const int p = b * 1024 + hw0 + pl;
                unsigned short u[8];
                #pragma unroll
                for (int j = 0; j < 8; ++j) u[j] = f2bf(t[ch * 8 + j][pl]);
                *(uint4*)(zfbT + ((size_t)((dc >> 3) + ch) * NPTS + p) * 8) = *(uint4*)u;
            }
            __syncthreads();
        }
    }
}

// ================= 256x256 8-phase GEMM core (round-7 structure: session best) =================
#define SBAR  __builtin_amdgcn_sched_barrier(0);
#define BARR  __builtin_amdgcn_s_barrier();
#define VMC(N) asm volatile("s_waitcnt vmcnt(" N ")");
#define LGKM_SB  asm volatile("s_waitcnt lgkmcnt(0)"); __builtin_amdgcn_sched_barrier(0);

#define STG_A(slot, t, kk)                                                          \
    do {                                                                            \
        const int cA1_ = (kk) * 4 + hi_, cA2_ = (kk) * 4 + 2 + hi_;                 \
        gload16(zfbT + ((size_t)((t) * 8 + cA1_) * NPTS + m0 + (th_ ^ (cA1_ << 1))) * 8, \
                &sA[slot][cA1_][th_][0]);                                           \
        gload16(zfbT + ((size_t)((t) * 8 + cA2_) * NPTS + m0 + (th_ ^ (cA2_ << 1))) * 8, \
                &sA[slot][cA2_][th_][0]);                                           \
    } while (0)

#define STG_B(slot, t, kk)                                                          \
    do {                                                                            \
        const int cB1_ = (kk) * 4 + hi_, cB2_ = (kk) * 4 + 2 + hi_;                 \
        gload16(ewbT + ((size_t)((t) * 8 + cB1_) * K + n0 + (th_ ^ (cB1_ << 1))) * 8, \
                &sB[slot][cB1_][th_][0]);                                           \
        gload16(ewbT + ((size_t)((t) * 8 + cB2_) * K + n0 + (th_ ^ (cB2_ << 1))) * 8, \
                &sB[slot][cB2_][th_][0]);                                           \
    } while (0)

#define RD_A(slot, kO, mg)                                                          \
    do {                                                                            \
        const unsigned a__ = sAb_ + (unsigned)((slot) * 32768 + (mg) * 1024) + (kO);\
        asm volatile("ds_read_b128 %0, %1"            : "=v"(af_[0]) : "v"(a__));   \
        asm volatile("ds_read_b128 %0, %1 offset:256" : "=v"(af_[1]) : "v"(a__));   \
        asm volatile("ds_read_b128 %0, %1 offset:512" : "=v"(af_[2]) : "v"(a__));   \
        asm volatile("ds_read_b128 %0, %1 offset:768" : "=v"(af_[3]) : "v"(a__));   \
    } while (0)

#define RD_B(slot, kO)                                                              \
    do {                                                                            \
        const unsigned b__ = sBb_ + (unsigned)((slot) * 32768) + (kO);              \
        asm volatile("ds_read_b128 %0, %1"            : "=v"(bf_[0]) : "v"(b__));   \
        asm volatile("ds_read_b128 %0, %1 offset:256" : "=v"(bf_[1]) : "v"(b__));   \
        asm volatile("ds_read_b128 %0, %1 offset:512" : "=v"(bf_[2]) : "v"(b__));   \
        asm volatile("ds_read_b128 %0, %1 offset:768" : "=v"(bf_[3]) : "v"(b__));   \
    } while (0)

#define MF(mg)                                                                      \
    do {                                                                            \
        __builtin_amdgcn_s_setprio(1);                                              \
        _Pragma("unroll")                                                           \
        for (int j_ = 0; j_ < 4; ++j_)                                              \
            _Pragma("unroll")                                                       \
            for (int nt_ = 0; nt_ < 4; ++nt_)                                       \
                acc[(mg) * 4 + j_][nt_] = __builtin_amdgcn_mfma_f32_16x16x32_bf16(  \
                    af_[j_], bf_[nt_], acc[(mg) * 4 + j_][nt_], 0, 0, 0);           \
        __builtin_amdgcn_s_setprio(0);                                              \
    } while (0)

#define KTILE(slot, SA0, SB0, SA1, SB1, V1, V2)                                     \
    RD_A(slot, aOff0_, 0); RD_B(slot, bOff0_); SA0; SBAR BARR LGKM_SB MF(0); SBAR BARR SBAR \
    RD_A(slot, aOff0_, 1);                     SB0; SBAR BARR LGKM_SB MF(1); SBAR VMC(V1) BARR SBAR \
    RD_A(slot, aOff1_, 0); RD_B(slot, bOff1_); SA1; SBAR BARR LGKM_SB MF(0); SBAR BARR SBAR \
    RD_A(slot, aOff1_, 1);                     SB1; SBAR BARR LGKM_SB MF(1); SBAR V2 BARR SBAR

#define GEMM_CORE()                                                                 \
    __shared__ unsigned short sA[2][8][256][8];                                     \
    __shared__ unsigned short sB[2][8][256][8];                                     \
    f32x4 acc[8][4];                                                                \
    _Pragma("unroll")                                                               \
    for (int i_ = 0; i_ < 8; ++i_)                                                  \
        _Pragma("unroll")                                                           \
        for (int j_ = 0; j_ < 4; ++j_) acc[i_][j_] = (f32x4){0.f, 0.f, 0.f, 0.f};   \
    bf16x8 af_[4], bf_[4];                                                          \
    const int th_ = tid & 255, hi_ = tid >> 8;                                      \
    const int aRow_ = wm * 128 + col, bRow_ = wn * 64 + col;                        \
    const unsigned sAb_ = lds_off(&sA[0][0][0][0]);                                 \
    const unsigned sBb_ = lds_off(&sB[0][0][0][0]);                                 \
    const int ck0_ = quad, ck1_ = 4 + quad;                                         \
    const unsigned aOff0_ = (unsigned)((ck0_ * 256 + (aRow_ ^ (ck0_ << 1))) * 16);  \
    const unsigned aOff1_ = (unsigned)((ck1_ * 256 + (aRow_ ^ (ck1_ << 1))) * 16);  \
    const unsigned bOff0_ = (unsigned)((ck0_ * 256 + (bRow_ ^ (ck0_ << 1))) * 16);  \
    const unsigned bOff1_ = (unsigned)((ck1_ * 256 + (bRow_ ^ (ck1_ << 1))) * 16);  \
    STG_A(0, 0, 0); STG_B(0, 0, 0); STG_A(0, 0, 1); STG_B(0, 0, 1);                 \
    SBAR VMC("4") BARR SBAR                                                         \
    KTILE(0, STG_A(1, 1, 0), STG_B(1, 1, 0), STG_A(1, 1, 1), STG_B(1, 1, 1), "4", VMC("4")) \
    KTILE(1, STG_A(0, 2, 0), STG_B(0, 2, 0), STG_A(0, 2, 1), STG_B(0, 2, 1), "4", VMC("4")) \
    KTILE(0, STG_A(1, 3, 0), STG_B(1, 3, 0), STG_A(1, 3, 1), STG_B(1, 3, 1), "4", VMC("4")) \
    KTILE(1, , , , , "0", )

// wave-aggregated global overflow append (round-3 lesson: per-candidate same-address
// atomics serialize catastrophically)
#define CAND_APPEND(e)                                                              \
    do {                                                                            \
        const u64 am_ = __builtin_amdgcn_read_exec();                               \
        const unsigned n_ = (unsigned)__popcll(am_);                                \
        const unsigned rk_ = (unsigned)__popcll(am_ & ((1ull << lane) - 1));        \
        unsigned base_ = 0;                                                         \
        if (rk_ == 0) base_ = atomicAdd(cnt, n_);                                   \
        base_ = (unsigned)__builtin_amdgcn_readfirstlane((int)base_);               \
        const unsigned g_ = base_ + rk_;                                            \
        if (g_ < cap) cand[g_] = (e);                                               \
    } while (0)

// XCD-chunked bijective decode (1-D grid, xcd = bid & 7)
#define XCD_DECODE(NT0)                                                             \
    const unsigned bid_ = blockIdx.x;                                               \
    const unsigned j_ = bid_ >> 3;                                                  \
    const int m0 = (int)(((bid_ & 7u) << 2) | (j_ & 3u)) * 256;                     \
    const int n0 = (NT0) + (int)(j_ >> 2) * 256;

// ---- phase 1: codes [0,2048). Self-seeded thresholds; publishes block max at exit. ----
__global__ __launch_bounds__(512, 2) void score_seed(const unsigned short* __restrict__ zfbT,
                                                     const unsigned short* __restrict__ ewbT,
                                                     unsigned* __restrict__ gmax,
                                                     u64* __restrict__ cand,
                                                     unsigned* __restrict__ cnt,
                                                     unsigned cap) {
    __shared__ unsigned thrS[256];
    __shared__ u64 lbuf[LCAP];
    __shared__ unsigned lcount, lbase;

    const int tid = threadIdx.x, lane = tid & 63, wave = tid >> 6;
    const int quad = lane >> 4, col = lane & 15;
    const int wm = wave >> 2, wn = wave & 3;
    XCD_DECODE(0)
    const int shsrc = lane & 48;

    if (tid < 256) thrS[tid] = 0u;
    if (tid == 0) lcount = 0u;

    GEMM_CORE()
    __syncthreads();   // all waves done with GEMM; publish thrS/lcount init before epilogue

    float red[8][4];
    #pragma unroll
    for (int mt = 0; mt < 8; ++mt)
        #pragma unroll
        for (int r = 0; r < 4; ++r)
            red[mt][r] = fmaxf(fmaxf(acc[mt][0][r], acc[mt][1][r]),
                               fmaxf(acc[mt][2][r], acc[mt][3][r]));
    #pragma unroll
    for (int off = 1; off < 16; off <<= 1)
        #pragma unroll
        for (int mt = 0; mt < 8; ++mt)
            #pragma unroll
            for (int r = 0; r < 4; ++r)
                red[mt][r] = fmaxf(red[mt][r], __shfl_xor(red[mt][r], off));
    #pragma unroll
    for (int mt = 0; mt < 8; ++mt)
        #pragma unroll
        for (int r = 0; r < 4; ++r) {
            const int pl = wm * 128 + mt * 16 + quad * 4 + r;
            unsigned cur = 0;
            if (col == 0) {
                const unsigned enc = f2s(red[mt][r]);
                const unsigned old = atomicMax(&thrS[pl], enc);
                cur = old > enc ? old : enc;
            }
            cur = (unsigned)__shfl((int)cur, shsrc);
            red[mt][r] = s2f(cur) - DELTA;
        }

    const int ncode0 = n0 + wn * 64 + col;
    #pragma unroll
    for (int mt = 0; mt < 8; ++mt) {
        #pragma unroll
        for (int r = 0; r < 4; ++r) {
            const float tp = red[mt][r];
            const unsigned pt = m0 + wm * 128 + mt * 16 + quad * 4 + r;
            #pragma unroll
            for (int nt = 0; nt < 4; ++nt) {
                const float v = acc[mt][nt][r];
                if (v >= tp) {
                    const unsigned slot = atomicAdd(&lcount, 1u);
                    const u64 e = ((u64)((pt << 14) | (unsigned)(ncode0 + nt * 16)) << 32)
                                  | f2s(v);
                    if (slot < LCAP) lbuf[slot] = e;
                    else CAND_APPEND(e);
                }
            }
        }
    }

    __syncthreads();
    if (tid < 256) atomicMax(&gmax[m0 + tid], thrS[tid]);
    const unsigned m_ = lcount < LCAP ? lcount : LCAP;
    if (tid == 0) lbase = atomicAdd(cnt, m_);
    __syncthreads();
    for (unsigned i = tid; i < m_; i += 512) {
        const unsigned g = lbase + i;
        if (g < cap) cand[g] = lbuf[i];
    }
}

// ---- phase 2: codes [2048,16384). Static thresholds from gmax. ----
__global__ __launch_bounds__(512, 2) void score_main(const unsigned short* __restrict__ zfbT,
                                                     const unsigned short* __restrict__ ewbT,
                                                     const unsigned* __restrict__ gmax,
                                                     u64* __restrict__ cand,
                                                     unsigned* __restrict__ cnt,
                                                     unsigned cap) {
    __shared__ float thrL[256];
    __shared__ u64 lbuf[LCAP];
    __shared__ unsigned lcount, lbase;

    const int tid = threadIdx.x, lane = tid & 63, wave = tid >> 6;
    const int quad = lane >> 4, col = lane & 15;
    const int wm = wave >> 2, wn = wave & 3;
    XCD_DECODE(2048)

    if (tid < 256) thrL[tid] = s2f(gmax[m0 + tid]) - DELTA;
    if (tid == 0) lcount = 0u;

    GEMM_CORE()
    __syncthreads();   // all waves done with GEMM; publish thrL/lcount init before epilogue

    const int ncode0 = n0 + wn * 64 + col;
    #pragma unroll
    for (int mt = 0; mt < 8; ++mt) {
        #pragma unroll
        for (int r = 0; r < 4; ++r) {
            const int pl = wm * 128 + mt * 16 + quad * 4 + r;
            const float tp = thrL[pl];
            #pragma unroll
            for (int nt = 0; nt < 4; ++nt) {
                const float v = acc[mt][nt][r];
                if (v >= tp) {
                    const unsigned slot = atomicAdd(&lcount, 1u);
                    const u64 e = ((u64)(((unsigned)pl + m0) << 14 | (unsigned)(ncode0 + nt * 16)) << 32)
                                  | f2s(v);
                    if (slot < LCAP) lbuf[slot] = e;
                    else CAND_APPEND(e);
                }
            }
        }
    }

    __syncthreads();
    const unsigned m_ = lcount < LCAP ? lcount : LCAP;
    if (tid == 0) lbase = atomicAdd(cnt, m_);
    __syncthreads();
    for (unsigned i = tid; i < m_; i += 512) {
        const unsigned g = lbase + i;
        if (g < cap) cand[g] = lbuf[i];
    }
}

// ---- final per-point bf16 max over candidates ----
__global__ __launch_bounds__(256) void cand_max(const u64* __restrict__ cand,
                                                const unsigned* __restrict__ cnt,
                                                unsigned* __restrict__ gmax,
                                                unsigned cap) {
    const unsigned total = min(cnt[0], cap);
    const unsigned stride = gridDim.x * 256;
    for (unsigned i = blockIdx.x * 256 + threadIdx.x; i < total; i += stride) {
        const u64 e = cand[i];
        atomicMax(&gmax[(unsigned)(e >> 46)], (unsigned)(e & 0xffffffffull));
    }
}

// ---- lane-parallel filter + ballot-compacted wave-cooperative fp32 rescore ----
__global__ __launch_bounds__(256) void rescore(const float* __restrict__ zf32,
                                               const float* __restrict__ E,
                                               const float* __restrict__ den,
                                               const unsigned* __restrict__ gmax,
                                               const u64* __restrict__ cand,
                                               const unsigned* __restrict__ cnt,
                                               u64* __restrict__ keys,
                                               unsigned cap) {
    const unsigned total = min(cnt[0], cap);
    const int lane = threadIdx.x & 63;
    const unsigned w = (blockIdx.x * 256 + threadIdx.x) >> 6;
    const unsigned nw = gridDim.x * 4;
    for (unsigned base = w * 64; base < total; base += nw * 64) {
        const unsigned i = base + lane;
        u64 e = 0;
        bool keep = false;
        if (i < total) {
            e = cand[i];
            const int p = (int)(e >> 46);
            keep = (s2f((unsigned)(e & 0xffffffffull)) >= s2f(gmax[p]) - DELTA);
        }
        u64 mask = __ballot(keep);
        while (mask) {
            const int src = __ffsll((long long)mask) - 1;
            mask &= mask - 1;
            const unsigned pc = (unsigned)__shfl((int)(unsigned)(e >> 32), src);
            const int p = pc >> 14, c = pc & 16383;
            const float dinv = 1.0f / den[c];
            const float4 a = *(const float4*)(zf32 + (size_t)p * D + lane * 4);
            const float4 b = *(const float4*)(E + (size_t)c * D + lane * 4);
            float sv = fmaf(a.x, b.x * dinv, fmaf(a.y, b.y * dinv,
                       fmaf(a.z, b.z * dinv, a.w * (b.w * dinv))));
            #pragma unroll
            for (int o = 1; o < 64; o <<= 1) sv += __shfl_xor(sv, o);
            if (lane == 0)
                atomicMax(keys + p, ((u64)f2s(sv) << 32) | (unsigned)(16383 - c));
        }
    }
}

// ---- gather + outputs (LDS transpose for coalesced zq writes) ----
__global__ __launch_bounds__(256) void finalize(const float* __restrict__ E,
                                                const float* __restrict__ den,
                                                const u64* __restrict__ keys,
                                                float* __restrict__ out) {
    __shared__ float t[32][257];
    __shared__ int sIdx[32];
    __shared__ float sDen[32];
    const int tid = threadIdx.x;
    const int n0 = blockIdx.x * 32;
    if (tid < 32) {
        const u64 key = keys[n0 + tid];
        const int idx = 16383 - (int)(unsigned)(key & 0xffffffffull);
        sIdx[tid] = idx;
        sDen[tid] = den[idx];
        out[O_IDX + n0 + tid] = (float)idx;
    }
    __syncthreads();
    const float S = 5.65685424949238019520675489683895f;  // sqrt(32)
    #pragma unroll 4
    for (int i = 0; i < 32; ++i) {
        const float v = E[(size_t)sIdx[i] * D + tid] / sDen[i];
        t[i][tid] = v;
        out[O_BIT + (size_t)(n0 + i) * D + tid] = (float)((int)(v * S) + 4);
    }
    __syncthreads();
    const int b = n0 >> 10, hw0 = n0 & 1023;
    const int hwl = tid & 31, cg = tid >> 5;
    #pragma unroll 4
    for (int cc = 0; cc < 32; ++cc) {
        const int c = cc * 8 + cg;
        out[(size_t)(b * 256 + c) * 1024 + hw0 + hwl] = t[hwl][c];
    }
    if (n0 == 0 && tid == 0) out[O_LOSS] = 0.0f;
}

extern "C" void kernel_launch(void* const* d_in, const int* in_sizes, int n_in,
                              void* d_out, int out_size, void* d_ws, size_t ws_size,
                              hipStream_t stream) {
    const float* z = (const float*)d_in[0];
    const float* E = (const float*)d_in[1];
    float* out = (float*)d_out;

    char* w = (char*)d_ws;
    unsigned short* ewbT = (unsigned short*)w;  w += (size_t)K * D * 2;      //  8 MB
    unsigned short* zfbT = (unsigned short*)w;  w += (size_t)NPTS * D * 2;   //  4 MB
    float*          zf32 = (float*)w;           w += (size_t)NPTS * D * 4;   //  8 MB
    u64*            keys = (u64*)w;             w += (size_t)NPTS * 8;       // 64 KB
    float*          den  = (float*)w;           w += (size_t)K * 4;          // 64 KB
    unsigned*       gmax = (unsigned*)w;        w += (size_t)NPTS * 4;       // 32 KB
    unsigned*       cnt  = (unsigned*)w;        w += 256;
    u64*            cand = (u64*)w;             // remainder of ws
    const size_t fixed = (size_t)(w - (char*)d_ws);
    const size_t avail = ws_size > fixed ? (ws_size - fixed) / 8 : 0;
    const unsigned cap = (unsigned)(avail < (size_t)MAXCAP ? avail : (size_t)MAXCAP);

    prep<<<640, 256, 0, stream>>>(E, z, den, ewbT, zfbT, zf32, gmax, keys, cnt);

    score_seed<<<256, 512, 0, stream>>>(zfbT, ewbT, gmax, cand, cnt, cap);
    score_main<<<1792, 512, 0, stream>>>(zfbT, ewbT, gmax, cand, cnt, cap);

    cand_max<<<256, 256, 0, stream>>>(cand, cnt, gmax, cap);
    rescore<<<1024, 256, 0, stream>>>(zf32, E, den, gmax, cand, cnt, keys, cap);
    finalize<<<NPTS / 32, 256, 0, stream>>>(E, den, keys, out);
}

// Round 13
// 229.193 us; speedup vs baseline: 6.4245x; 1.0228x over previous
//
#include <hip/hip_runtime.h>
#include <math.h>

#define D      256
#define K      16384
#define NPTS   8192
#define DELTA  0.2f
#define LCAP   2048
#define MAXCAP 4000000u

// d_out layout (all f32): zq[8,256,32,32] | indices[8192] | bit[8,32,32,256] | loss[1]
#define O_IDX  2097152
#define O_BIT  2105344
#define O_LOSS 4202496

typedef __attribute__((ext_vector_type(8))) short bf16x8;
typedef __attribute__((ext_vector_type(4))) float f32x4;
typedef unsigned long long u64;

__device__ __forceinline__ unsigned f2s(float f) {
    unsigned u = __float_as_uint(f);
    return (u & 0x80000000u) ? ~u : (u | 0x80000000u);
}
__device__ __forceinline__ float s2f(unsigned s) {
    return __uint_as_float((s & 0x80000000u) ? (s & 0x7fffffffu) : ~s);
}
__device__ __forceinline__ unsigned short f2bf(float f) {  // RNE
    unsigned u = __float_as_uint(f);
    u += 0x7fffu + ((u >> 16) & 1u);
    return (unsigned short)(u >> 16);
}

// async global->LDS, 16B per lane (wave-uniform base + lane*16 dest)
__device__ __forceinline__ void gload16(const unsigned short* g, unsigned short* l) {
    __builtin_amdgcn_global_load_lds(
        (const __attribute__((address_space(1))) unsigned int*)g,
        (__attribute__((address_space(3))) unsigned int*)l, 16, 0, 0);
}

// generic LDS pointer -> 32-bit LDS byte offset for inline-asm ds_read
__device__ __forceinline__ unsigned lds_off(const void* p) {
    return (unsigned)(size_t)(const __attribute__((address_space(3))) void*)p;
}

// k-major fragment layouts: X[(k>>3)][row][8] bf16, 16B per (row, k-chunk)
//   zfbT: [32][NPTS][8] bf16 ; ewbT: [32][K][8] bf16

// ---- merged prep: blocks [0,512) codebook; [512,640) z transpose; state init folded ----
__global__ __launch_bounds__(256) void prep(const float* __restrict__ E,
                                            const float* __restrict__ z,
                                            float* __restrict__ den,
                                            unsigned short* __restrict__ ewbT,
                                            unsigned short* __restrict__ zfbT,
                                            float* __restrict__ zf32,
                                            unsigned* __restrict__ gmax,
                                            u64* __restrict__ keys,
                                            unsigned* __restrict__ cnt) {
    const int blk = blockIdx.x, tid = threadIdx.x;
    if (blk < 512) {
        const int lane = tid & 63, wave = tid >> 6;
        if (blk < 32)        gmax[blk * 256 + tid] = 0u;
        else if (blk < 64)   keys[(blk - 32) * 256 + tid] = 0ull;
        else if (blk == 64 && tid < 2) cnt[tid] = 0u;
        #pragma unroll
        for (int j = 0; j < 8; ++j) {
            const int row = blk * 32 + wave * 8 + j;
            const float4 v = *(const float4*)(E + (size_t)row * D + lane * 4);
            float ss = v.x * v.x + v.y * v.y + v.z * v.z + v.w * v.w;
            #pragma unroll
            for (int o = 1; o < 64; o <<= 1) ss += __shfl_xor(ss, o);
            const float dn = fmaxf(sqrtf(ss), 1e-12f);
            const unsigned lo = (unsigned)f2bf(v.x / dn) | ((unsigned)f2bf(v.y / dn) << 16);
            const unsigned hi = (unsigned)f2bf(v.z / dn) | ((unsigned)f2bf(v.w / dn) << 16);
            // k = lane*4 .. +4 -> chunk lane>>1, offset (lane&1)*4
            *(uint2*)(ewbT + ((size_t)(lane >> 1) * K + row) * 8 + (lane & 1) * 4)
                = make_uint2(lo, hi);
            if (lane == 0) den[row] = dn;
        }
    } else {
        const int bi = blk - 512;
        const int b = bi >> 4, hw0 = (bi & 15) * 64;
        __shared__ float t[64][65];
        for (int dc = 0; dc < D; dc += 64) {
            #pragma unroll
            for (int it = 0; it < 16; ++it) {
                const int idx = it * 256 + tid;
                const int dl = idx >> 6, hw = idx & 63;
                t[dl][hw] = z[(size_t)(b * 256 + dc + dl) * 1024 + hw0 + hw];
            }
            __syncthreads();
            // zf32: coalesced f32 writes
            #pragma unroll
            for (int it = 0; it < 16; ++it) {
                const int idx = it * 256 + tid;
                const int pl = idx >> 6, dl = idx & 63;
                zf32[(size_t)(b * 1024 + hw0 + pl) * D + dc + dl] = t[dl][pl];
            }
            // zfbT: vectorized 16B coalesced stores
            #pragma unroll
            for (int tk = 0; tk < 2; ++tk) {
                const int task = tk * 256 + tid;
                const int ch = task >> 6, pl = task & 63;
                const int p = b * 1024 + hw0 + pl;
                unsigned short u[8];
                #pragma unroll
                for (int j = 0; j < 8; ++j) u[j] = f2bf(t[ch * 8 + j][pl]);
                *(uint4*)(zfbT + ((size_t)((dc >> 3) + ch) * NPTS + p) * 8) = *(uint4*)u;
            }
            __syncthreads();
        }
    }
}

// ================= 256x256 GEMM core, minimal-barrier (round 13) =================
// r12 structure with the 6 superfluous barriers per K-tile removed. Licensing ledger
// (re-derived, unchanged semantics):
//  - prologue: 8 loads issued (kk0 then kk1 of tile 0); VMC(4) retires the oldest 4
//    (= kk0, FIFO per m135); BARR converts my-retirement -> all-waves. kk0 licensed.
//  - per tile: phases issue SA0,SB0 (kk0 of tile t+1, 4 loads) then mid VMC(4)+BARR:
//    outstanding = [t.kk1(4), SA0,SB0(4)] -> retires t.kk1. kk1 licensed.
//    phases issue SA1,SB1 (4 loads); tile-end VMC(4)+BARR retires SA0+SB0 = (t+1).kk0.
//  - slot overwrite: STG(t+1 -> slot^1) issues after the tile-start barrier, which every
//    wave reaches only after its last LGKM(0) drained all its slot^1 reads (tile t-1).
//  Per-wave vmcnt counting is valid WITHOUT lockstep: every wave issues the identical
//  load sequence in the same order. So waves may slip phases freely between licensing
//  barriers -> wave A's MFMA burst overlaps wave B's ds_read/lgkm wait (the cross-wave
//  overlap r8's probes proved the HW delivers; lockstep was suppressing it, and why
//  setprio had no role diversity to exploit).
#define SBAR  __builtin_amdgcn_sched_barrier(0);
#define BARR  __builtin_amdgcn_s_barrier();
#define VMC(N) asm volatile("s_waitcnt vmcnt(" N ")");
#define LGKM_SB  asm volatile("s_waitcnt lgkmcnt(0)"); __builtin_amdgcn_sched_barrier(0);

#define STG_A(slot, t, kk)                                                          \
    do {                                                                            \
        const int cA1_ = (kk) * 4 + hi_, cA2_ = (kk) * 4 + 2 + hi_;                 \
        gload16(zfbT + ((size_t)((t) * 8 + cA1_) * NPTS + m0 + (th_ ^ (cA1_ << 1))) * 8, \
                &sA[slot][cA1_][th_][0]);                                           \
        gload16(zfbT + ((size_t)((t) * 8 + cA2_) * NPTS + m0 + (th_ ^ (cA2_ << 1))) * 8, \
                &sA[slot][cA2_][th_][0]);                                           \
    } while (0)

#define STG_B(slot, t, kk)                                                          \
    do {                                                                            \
        const int cB1_ = (kk) * 4 + hi_, cB2_ = (kk) * 4 + 2 + hi_;                 \
        gload16(ewbT + ((size_t)((t) * 8 + cB1_) * K + n0 + (th_ ^ (cB1_ << 1))) * 8, \
                &sB[slot][cB1_][th_][0]);                                           \
        gload16(ewbT + ((size_t)((t) * 8 + cB2_) * K + n0 + (th_ ^ (cB2_ << 1))) * 8, \
                &sB[slot][cB2_][th_][0]);                                           \
    } while (0)

#define RD_A(slot, kO, mg)                                                          \
    do {                                                                            \
        const unsigned a__ = sAb_ + (unsigned)((slot) * 32768 + (mg) * 1024) + (kO);\
        asm volatile("ds_read_b128 %0, %1"            : "=v"(af_[0]) : "v"(a__));   \
        asm volatile("ds_read_b128 %0, %1 offset:256" : "=v"(af_[1]) : "v"(a__));   \
        asm volatile("ds_read_b128 %0, %1 offset:512" : "=v"(af_[2]) : "v"(a__));   \
        asm volatile("ds_read_b128 %0, %1 offset:768" : "=v"(af_[3]) : "v"(a__));   \
    } while (0)

#define RD_B(slot, kO)                                                              \
    do {                                                                            \
        const unsigned b__ = sBb_ + (unsigned)((slot) * 32768) + (kO);              \
        asm volatile("ds_read_b128 %0, %1"            : "=v"(bf_[0]) : "v"(b__));   \
        asm volatile("ds_read_b128 %0, %1 offset:256" : "=v"(bf_[1]) : "v"(b__));   \
        asm volatile("ds_read_b128 %0, %1 offset:512" : "=v"(bf_[2]) : "v"(b__));   \
        asm volatile("ds_read_b128 %0, %1 offset:768" : "=v"(bf_[3]) : "v"(b__));   \
    } while (0)

#define MF(mg)                                                                      \
    do {                                                                            \
        __builtin_amdgcn_s_setprio(1);                                              \
        _Pragma("unroll")                                                           \
        for (int j_ = 0; j_ < 4; ++j_)                                              \
            _Pragma("unroll")                                                       \
            for (int nt_ = 0; nt_ < 4; ++nt_)                                       \
                acc[(mg) * 4 + j_][nt_] = __builtin_amdgcn_mfma_f32_16x16x32_bf16(  \
                    af_[j_], bf_[nt_], acc[(mg) * 4 + j_][nt_], 0, 0, 0);           \
        __builtin_amdgcn_s_setprio(0);                                              \
    } while (0)

// Minimal-barrier K-tile: only the two LICENSING sync points remain.
#define KTILE(slot, SA0, SB0, SA1, SB1, V1, V2)                                     \
    RD_A(slot, aOff0_, 0); RD_B(slot, bOff0_); SA0; SBAR LGKM_SB MF(0); SBAR        \
    RD_A(slot, aOff0_, 1);                     SB0; SBAR LGKM_SB MF(1); SBAR        \
    SBAR VMC(V1) BARR SBAR  /* license kk1: retires t.kk1 loads, all-waves */       \
    RD_A(slot, aOff1_, 0); RD_B(slot, bOff1_); SA1; SBAR LGKM_SB MF(0); SBAR        \
    RD_A(slot, aOff1_, 1);                     SB1; SBAR LGKM_SB MF(1); SBAR        \
    SBAR V2 BARR SBAR       /* license (t+1).kk0: retires SA0/SB0, all-waves */

#define GEMM_CORE()                                                                 \
    __shared__ unsigned short sA[2][8][256][8];                                     \
    __shared__ unsigned short sB[2][8][256][8];                                     \
    f32x4 acc[8][4];                                                                \
    _Pragma("unroll")                                                               \
    for (int i_ = 0; i_ < 8; ++i_)                                                  \
        _Pragma("unroll")                                                           \
        for (int j_ = 0; j_ < 4; ++j_) acc[i_][j_] = (f32x4){0.f, 0.f, 0.f, 0.f};   \
    bf16x8 af_[4], bf_[4];                                                          \
    const int th_ = tid & 255, hi_ = tid >> 8;                                      \
    const int aRow_ = wm * 128 + col, bRow_ = wn * 64 + col;                        \
    const unsigned sAb_ = lds_off(&sA[0][0][0][0]);                                 \
    const unsigned sBb_ = lds_off(&sB[0][0][0][0]);                                 \
    const int ck0_ = quad, ck1_ = 4 + quad;                                         \
    const unsigned aOff0_ = (unsigned)((ck0_ * 256 + (aRow_ ^ (ck0_ << 1))) * 16);  \
    const unsigned aOff1_ = (unsigned)((ck1_ * 256 + (aRow_ ^ (ck1_ << 1))) * 16);  \
    const unsigned bOff0_ = (unsigned)((ck0_ * 256 + (bRow_ ^ (ck0_ << 1))) * 16);  \
    const unsigned bOff1_ = (unsigned)((ck1_ * 256 + (bRow_ ^ (ck1_ << 1))) * 16);  \
    STG_A(0, 0, 0); STG_B(0, 0, 0); STG_A(0, 0, 1); STG_B(0, 0, 1);                 \
    SBAR VMC("4") BARR SBAR                                                         \
    KTILE(0, STG_A(1, 1, 0), STG_B(1, 1, 0), STG_A(1, 1, 1), STG_B(1, 1, 1), "4", VMC("4")) \
    KTILE(1, STG_A(0, 2, 0), STG_B(0, 2, 0), STG_A(0, 2, 1), STG_B(0, 2, 1), "4", VMC("4")) \
    KTILE(0, STG_A(1, 3, 0), STG_B(1, 3, 0), STG_A(1, 3, 1), STG_B(1, 3, 1), "4", VMC("4")) \
    KTILE(1, , , , , "0", )

// wave-aggregated global overflow append (round-3 lesson: per-candidate same-address
// atomics serialize catastrophically)
#define CAND_APPEND(e)                                                              \
    do {                                                                            \
        const u64 am_ = __builtin_amdgcn_read_exec();                               \
        const unsigned n_ = (unsigned)__popcll(am_);                                \
        const unsigned rk_ = (unsigned)__popcll(am_ & ((1ull << lane) - 1));        \
        unsigned base_ = 0;                                                         \
        if (rk_ == 0) base_ = atomicAdd(cnt, n_);                                   \
        base_ = (unsigned)__builtin_amdgcn_readfirstlane((int)base_);               \
        const unsigned g_ = base_ + rk_;                                            \
        if (g_ < cap) cand[g_] = (e);                                               \
    } while (0)

// XCD-chunked bijective decode (1-D grid, xcd = bid & 7)
#define XCD_DECODE(NT0)                                                             \
    const unsigned bid_ = blockIdx.x;                                               \
    const unsigned j_ = bid_ >> 3;                                                  \
    const int m0 = (int)(((bid_ & 7u) << 2) | (j_ & 3u)) * 256;                     \
    const int n0 = (NT0) + (int)(j_ >> 2) * 256;

// ---- phase 1: codes [0,2048). Self-seeded thresholds; publishes block max at exit. ----
__global__ __launch_bounds__(512, 2) void score_seed(const unsigned short* __restrict__ zfbT,
                                                     const unsigned short* __restrict__ ewbT,
                                                     unsigned* __restrict__ gmax,
                                                     u64* __restrict__ cand,
                                                     unsigned* __restrict__ cnt,
                                                     unsigned cap) {
    __shared__ unsigned thrS[256];
    __shared__ u64 lbuf[LCAP];
    __shared__ unsigned lcount, lbase;

    const int tid = threadIdx.x, lane = tid & 63, wave = tid >> 6;
    const int quad = lane >> 4, col = lane & 15;
    const int wm = wave >> 2, wn = wave & 3;
    XCD_DECODE(0)
    const int shsrc = lane & 48;

    if (tid < 256) thrS[tid] = 0u;
    if (tid == 0) lcount = 0u;

    GEMM_CORE()
    __syncthreads();   // all waves done with GEMM; publish thrS/lcount init before epilogue

    float red[8][4];
    #pragma unroll
    for (int mt = 0; mt < 8; ++mt)
        #pragma unroll
        for (int r = 0; r < 4; ++r)
            red[mt][r] = fmaxf(fmaxf(acc[mt][0][r], acc[mt][1][r]),
                               fmaxf(acc[mt][2][r], acc[mt][3][r]));
    #pragma unroll
    for (int off = 1; off < 16; off <<= 1)
        #pragma unroll
        for (int mt = 0; mt < 8; ++mt)
            #pragma unroll
            for (int r = 0; r < 4; ++r)
                red[mt][r] = fmaxf(red[mt][r], __shfl_xor(red[mt][r], off));
    #pragma unroll
    for (int mt = 0; mt < 8; ++mt)
        #pragma unroll
        for (int r = 0; r < 4; ++r) {
            const int pl = wm * 128 + mt * 16 + quad * 4 + r;
            unsigned cur = 0;
            if (col == 0) {
                const unsigned enc = f2s(red[mt][r]);
                const unsigned old = atomicMax(&thrS[pl], enc);
                cur = old > enc ? old : enc;
            }
            cur = (unsigned)__shfl((int)cur, shsrc);
            red[mt][r] = s2f(cur) - DELTA;
        }

    const int ncode0 = n0 + wn * 64 + col;
    #pragma unroll
    for (int mt = 0; mt < 8; ++mt) {
        #pragma unroll
        for (int r = 0; r < 4; ++r) {
            const float tp = red[mt][r];
            const unsigned pt = m0 + wm * 128 + mt * 16 + quad * 4 + r;
            #pragma unroll
            for (int nt = 0; nt < 4; ++nt) {
                const float v = acc[mt][nt][r];
                if (v >= tp) {
                    const unsigned slot = atomicAdd(&lcount, 1u);
                    const u64 e = ((u64)((pt << 14) | (unsigned)(ncode0 + nt * 16)) << 32)
                                  | f2s(v);
                    if (slot < LCAP) lbuf[slot] = e;
                    else CAND_APPEND(e);
                }
            }
        }
    }

    __syncthreads();
    if (tid < 256) atomicMax(&gmax[m0 + tid], thrS[tid]);
    const unsigned m_ = lcount < LCAP ? lcount : LCAP;
    if (tid == 0) lbase = atomicAdd(cnt, m_);
    __syncthreads();
    for (unsigned i = tid; i < m_; i += 512) {
        const unsigned g = lbase + i;
        if (g < cap) cand[g] = lbuf[i];
    }
}

// ---- phase 2: codes [2048,16384). Static thresholds from gmax. ----
__global__ __launch_bounds__(512, 2) void score_main(const unsigned short* __restrict__ zfbT,
                                                     const unsigned short* __restrict__ ewbT,
                                                     const unsigned* __restrict__ gmax,
                                                     u64* __restrict__ cand,
                                                     unsigned* __restrict__ cnt,
                                                     unsigned cap) {
    __shared__ float thrL[256];
    __shared__ u64 lbuf[LCAP];
    __shared__ unsigned lcount, lbase;

    const int tid = threadIdx.x, lane = tid & 63, wave = tid >> 6;
    const int quad = lane >> 4, col = lane & 15;
    const int wm = wave >> 2, wn = wave & 3;
    XCD_DECODE(2048)

    if (tid < 256) thrL[tid] = s2f(gmax[m0 + tid]) - DELTA;
    if (tid == 0) lcount = 0u;

    GEMM_CORE()
    __syncthreads();   // all waves done with GEMM; publish thrL/lcount init before epilogue

    const int ncode0 = n0 + wn * 64 + col;
    #pragma unroll
    for (int mt = 0; mt < 8; ++mt) {
        #pragma unroll
        for (int r = 0; r < 4; ++r) {
            const int pl = wm * 128 + mt * 16 + quad * 4 + r;
            const float tp = thrL[pl];
            #pragma unroll
            for (int nt = 0; nt < 4; ++nt) {
                const float v = acc[mt][nt][r];
                if (v >= tp) {
                    const unsigned slot = atomicAdd(&lcount, 1u);
                    const u64 e = ((u64)(((unsigned)pl + m0) << 14 | (unsigned)(ncode0 + nt * 16)) << 32)
                                  | f2s(v);
                    if (slot < LCAP) lbuf[slot] = e;
                    else CAND_APPEND(e);
                }
            }
        }
    }

    __syncthreads();
    const unsigned m_ = lcount < LCAP ? lcount : LCAP;
    if (tid == 0) lbase = atomicAdd(cnt, m_);
    __syncthreads();
    for (unsigned i = tid; i < m_; i += 512) {
        const unsigned g = lbase + i;
        if (g < cap) cand[g] = lbuf[i];
    }
}

// ---- final per-point bf16 max over candidates ----
__global__ __launch_bounds__(256) void cand_max(const u64* __restrict__ cand,
                                                const unsigned* __restrict__ cnt,
                                                unsigned* __restrict__ gmax,
                                                unsigned cap) {
    const unsigned total = min(cnt[0], cap);
    const unsigned stride = gridDim.x * 256;
    for (unsigned i = blockIdx.x * 256 + threadIdx.x; i < total; i += stride) {
        const u64 e = cand[i];
        atomicMax(&gmax[(unsigned)(e >> 46)], (unsigned)(e & 0xffffffffull));
    }
}

// ---- lane-parallel filter + ballot-compacted wave-cooperative fp32 rescore ----
__global__ __launch_bounds__(256) void rescore(const float* __restrict__ zf32,
                                               const float* __restrict__ E,
                                               const float* __restrict__ den,
                                               const unsigned* __restrict__ gmax,
                                               const u64* __restrict__ cand,
                                               const unsigned* __restrict__ cnt,
                                               u64* __restrict__ keys,
                                               unsigned cap) {
    const unsigned total = min(cnt[0], cap);
    const int lane = threadIdx.x & 63;
    const unsigned w = (blockIdx.x * 256 + threadIdx.x) >> 6;
    const unsigned nw = gridDim.x * 4;
    for (unsigned base = w * 64; base < total; base += nw * 64) {
        const unsigned i = base + lane;
        u64 e = 0;
        bool keep = false;
        if (i < total) {
            e = cand[i];
            const int p = (int)(e >> 46);
            keep = (s2f((unsigned)(e & 0xffffffffull)) >= s2f(gmax[p]) - DELTA);
        }
        u64 mask = __ballot(keep);
        while (mask) {
            const int src = __ffsll((long long)mask) - 1;
            mask &= mask - 1;
            const unsigned pc = (unsigned)__shfl((int)(unsigned)(e >> 32), src);
            const int p = pc >> 14, c = pc & 16383;
            const float dinv = 1.0f / den[c];
            const float4 a = *(const float4*)(zf32 + (size_t)p * D + lane * 4);
            const float4 b = *(const float4*)(E + (size_t)c * D + lane * 4);
            float sv = fmaf(a.x, b.x * dinv, fmaf(a.y, b.y * dinv,
                       fmaf(a.z, b.z * dinv, a.w * (b.w * dinv))));
            #pragma unroll
            for (int o = 1; o < 64; o <<= 1) sv += __shfl_xor(sv, o);
            if (lane == 0)
                atomicMax(keys + p, ((u64)f2s(sv) << 32) | (unsigned)(16383 - c));
        }
    }
}

// ---- gather + outputs (LDS transpose for coalesced zq writes) ----
__global__ __launch_bounds__(256) void finalize(const float* __restrict__ E,
                                                const float* __restrict__ den,
                                                const u64* __restrict__ keys,
                                                float* __restrict__ out) {
    __shared__ float t[32][257];
    __shared__ int sIdx[32];
    __shared__ float sDen[32];
    const int tid = threadIdx.x;
    const int n0 = blockIdx.x * 32;
    if (tid < 32) {
        const u64 key = keys[n0 + tid];
        const int idx = 16383 - (int)(unsigned)(key & 0xffffffffull);
        sIdx[tid] = idx;
        sDen[tid] = den[idx];
        out[O_IDX + n0 + tid] = (float)idx;
    }
    __syncthreads();
    const float S = 5.65685424949238019520675489683895f;  // sqrt(32)
    #pragma unroll 4
    for (int i = 0; i < 32; ++i) {
        const float v = E[(size_t)sIdx[i] * D + tid] / sDen[i];
        t[i][tid] = v;
        out[O_BIT + (size_t)(n0 + i) * D + tid] = (float)((int)(v * S) + 4);
    }
    __syncthreads();
    const int b = n0 >> 10, hw0 = n0 & 1023;
    const int hwl = tid & 31, cg = tid >> 5;
    #pragma unroll 4
    for (int cc = 0; cc < 32; ++cc) {
        const int c = cc * 8 + cg;
        out[(size_t)(b * 256 + c) * 1024 + hw0 + hwl] = t[hwl][c];
    }
    if (n0 == 0 && tid == 0) out[O_LOSS] = 0.0f;
}

extern "C" void kernel_launch(void* const* d_in, const int* in_sizes, int n_in,
                              void* d_out, int out_size, void* d_ws, size_t ws_size,
                              hipStream_t stream) {
    const float* z = (const float*)d_in[0];
    const float* E = (const float*)d_in[1];
    float* out = (float*)d_out;

    char* w = (char*)d_ws;
    unsigned short* ewbT = (unsigned short*)w;  w += (size_t)K * D * 2;      //  8 MB
    unsigned short* zfbT = (unsigned short*)w;  w += (size_t)NPTS * D * 2;   //  4 MB
    float*          zf32 = (float*)w;           w += (size_t)NPTS * D * 4;   //  8 MB
    u64*            keys = (u64*)w;             w += (size_t)NPTS * 8;       // 64 KB
    float*          den  = (float*)w;           w += (size_t)K * 4;          // 64 KB
    unsigned*       gmax = (unsigned*)w;        w += (size_t)NPTS * 4;       // 32 KB
    unsigned*       cnt  = (unsigned*)w;        w += 256;
    u64*            cand = (u64*)w;             // remainder of ws
    const size_t fixed = (size_t)(w - (char*)d_ws);
    const size_t avail = ws_size > fixed ? (ws_size - fixed) / 8 : 0;
    const unsigned cap = (unsigned)(avail < (size_t)MAXCAP ? avail : (size_t)MAXCAP);

    prep<<<640, 256, 0, stream>>>(E, z, den, ewbT, zfbT, zf32, gmax, keys, cnt);

    score_seed<<<256, 512, 0, stream>>>(zfbT, ewbT, gmax, cand, cnt, cap);
    score_main<<<1792, 512, 0, stream>>>(zfbT, ewbT, gmax, cand, cnt, cap);

    cand_max<<<256, 256, 0, stream>>>(cand, cnt, gmax, cap);
    rescore<<<1024, 256, 0, stream>>>(zf32, E, den, gmax, cand, cnt, keys, cap);
    finalize<<<NPTS / 32, 256, 0, stream>>>(E, den, keys, out);
}